// Round 19
// baseline (889.605 us; speedup 1.0000x reference)
//
#include <hip/hip_runtime.h>
#include <hip/hip_bf16.h>
#include <hip/hip_cooperative_groups.h>
#include <math.h>

// Sizes
#define BB 256
#define SS 64
#define EE 300
#define EPX 320   // X padded
#define KP 832    // 320 + 512
#define VV 30000
#define HH 512
#define H2 1024
#define DA 350
#define RR 8
#define CC 150
#define PP 16
#define CP 2400
#define NFLAG (SS * 2 * 4)

// Output layout (elements, fp32)
#define ATT_OFF    0L
#define CL_OFF     131072L
#define PRED_OFF   169472L
#define ROUTES_OFF 5084672L

typedef _Float16 f16;
typedef f16  f16x8 __attribute__((ext_vector_type(8)));
typedef f16  f16x4 __attribute__((ext_vector_type(4)));
typedef float f32x4 __attribute__((ext_vector_type(4)));

static __device__ __forceinline__ float sigmK(float x) { return 1.0f / (1.0f + expf(-x)); }

// ---------------------------------------------------------------------------
// Fused staging: X16 gather | W16 pack | ws1_16 pack | flag zero, one kernel.
// ---------------------------------------------------------------------------
#define NG_ ((long)SS * BB * EPX)        // 5,242,880
#define NW_ ((long)2 * 2048 * KP)        // 3,407,872
#define NS_ ((long)384 * 1024)           //   393,216
__global__ __launch_bounds__(256) void k_stage(
    const int* __restrict__ ids, const float* __restrict__ emb,
    const float* __restrict__ wihF, const float* __restrict__ whhF,
    const float* __restrict__ wihB, const float* __restrict__ whhB,
    const float* __restrict__ ws1,
    f16* __restrict__ X16, f16* __restrict__ W16, f16* __restrict__ ws1_16,
    unsigned* __restrict__ flags)
{
    const long idx = (long)blockIdx.x * 256 + threadIdx.x;
    if (idx < NG_) {
        const int e = (int)(idx % EPX);
        const int row = (int)(idx / EPX);
        const int s = row >> 8, b = row & 255;
        int tok = ids[(long)b * SS + s];
        if ((unsigned)tok >= (unsigned)VV) tok = 0;
        X16[idx] = (e < EE) ? (f16)emb[(long)tok * EE + e] : (f16)0.0f;
    } else if (idx < NG_ + NW_) {
        const long i2 = idx - NG_;
        const int dir = (int)(i2 / (2048 * KP));
        const int rem = (int)(i2 % (2048 * KP));
        const int j = rem / KP, k = rem % KP;
        const float* wih = dir ? wihB : wihF;
        const float* whh = dir ? whhB : whhF;
        float v;
        if (k < EE)        v = wih[(long)j * EE + k];
        else if (k < EPX)  v = 0.0f;
        else               v = whh[(long)j * HH + (k - EPX)];
        W16[i2] = (f16)v;
    } else if (idx < NG_ + NW_ + NS_) {
        const long i3 = idx - NG_ - NW_;
        const int j = (int)(i3 >> 10);
        ws1_16[i3] = (j < DA) ? (f16)ws1[i3] : (f16)0.0f;
    } else if (idx < NG_ + NW_ + NS_ + NFLAG) {
        flags[idx - NG_ - NW_ - NS_] = 0u;
    }
}

// capsT16[r][2432][1024] transposed; rows >= 2400 zero. LDS 32x32 tiles.
__global__ __launch_bounds__(256) void k_packcapsT(
    const float* __restrict__ caps, f16* __restrict__ capsT)
{
    __shared__ float t[32][33];
    const int r = blockIdx.z, k0 = blockIdx.x * 32, n0 = blockIdx.y * 32;
    const int tx = threadIdx.x & 31, ty = threadIdx.x >> 5;
    #pragma unroll
    for (int p = 0; p < 4; ++p) {
        const int k = k0 + ty + p * 8;
        const int n = n0 + tx;
        t[ty + p * 8][tx] = (n < CP) ? caps[((long)r * H2 + k) * CP + n] : 0.0f;
    }
    __syncthreads();
    #pragma unroll
    for (int p = 0; p < 4; ++p) {
        const int n = n0 + ty + p * 8;
        if (n < 2432)
            capsT[((long)r * 2432 + n) * H2 + k0 + tx] = (f16)t[tx][ty + p * 8];
    }
}

// ---------------------------------------------------------------------------
// Persistent LSTM v6 = v5 protocol with hs16 archive moved OFF the critical
// path (after flag post, coalesced from hstage; reads are >=2 barriers ahead
// of the next hstage overwrite). 256 blocks x 512 thr.
// dir = bid&1, bq = (bid>>1)&3, ut = bid>>3 (group bid&7 -> XCD-local).
// ONE poller per block (round-16 lesson: per-wave polling = 2.6x regression).
// ---------------------------------------------------------------------------
__global__ __launch_bounds__(512, 1) void p_lstm6(
    const f16* __restrict__ X16, f16* __restrict__ hs16,
    f16* __restrict__ hx, unsigned* __restrict__ flags,
    const f16* __restrict__ W16,
    const float* __restrict__ bihF, const float* __restrict__ bhhF,
    const float* __restrict__ bihB, const float* __restrict__ bhhB)
{
    __shared__ f16 Wl[4 * 26 * 64 * 8];   // 104 KB, fragment-ordered
    __shared__ f32x4 part[4][64][4];      // 16 KB
    __shared__ f16 hstage[64][16];        // 2 KB

    const int bid = blockIdx.x;
    const int dir = bid & 1;
    const int bq  = (bid >> 1) & 3;
    const int ut  = bid >> 3;
    const int u0  = ut * 16;
    const int b0  = bq * 64;
    const int tid = threadIdx.x;
    const int wave = tid >> 6, lane = tid & 63;
    const int bt = wave & 3, kh = wave >> 2;
    const int l15 = lane & 15;
    const int kgrp = (lane >> 4) * 8;

    // One-time weight gather into fragment order
    {
        const f16* Wsrc = W16 + (long)dir * 2048 * KP;
        for (int f = tid; f < 4 * 26 * 64; f += 512) {
            const int g  = f / (26 * 64);
            const int rm = f % (26 * 64);
            const int kt = rm >> 6, ln = rm & 63;
            const long src = ((long)g * HH + u0 + (ln & 15)) * KP + kt * 32 + ((ln >> 4) * 8);
            *(f16x8*)(Wl + (long)f * 8) = *(const f16x8*)(Wsrc + src);
        }
    }
    __syncthreads();

    const int arow = b0 + bt * 16 + l15;
    const int u = u0 + l15;
    const float* bi = dir ? bihB : bihF;
    const float* bh = dir ? bhhB : bhhF;
    const float bias0 = bi[u]          + bh[u];
    const float bias1 = bi[HH + u]     + bh[HH + u];
    const float bias2 = bi[2 * HH + u] + bh[2 * HH + u];
    const float bias3 = bi[3 * HH + u] + bh[3 * HH + u];
    const int rbase = (lane >> 4) * 4;
    float cc[4] = {0.f, 0.f, 0.f, 0.f};

    f32x4 xacc[4];
    const int xb = kh ? 5 : 0;
    auto computeX = [&](int se) {
        #pragma unroll
        for (int g = 0; g < 4; ++g) xacc[g] = (f32x4){0.f, 0.f, 0.f, 0.f};
        const f16* Xrow = X16 + ((long)se * BB + arow) * EPX;
        #pragma unroll
        for (int j = 0; j < 5; ++j) {
            const int kt = xb + j;
            const int k0 = kt * 32 + kgrp;
            const f16x8 afr = *(const f16x8*)(Xrow + k0);
            #pragma unroll
            for (int g = 0; g < 4; ++g) {
                const f16x8 bfr = *(const f16x8*)(Wl + (((g * 26 + kt) << 6) + lane) * 8);
                xacc[g] = __builtin_amdgcn_mfma_f32_16x16x32_f16(afr, bfr, xacc[g], 0, 0, 0);
            }
        }
    };
    computeX(dir ? (SS - 1) : 0);

    const int hb = kh ? 8 : 0;
    for (int s = 0; s < SS; ++s) {
        const int s_eff = dir ? (SS - 1 - s) : s;

        if (s > 0) {
            if (tid == 0) {
                const int fi = ((s - 1) * 2 + dir) * 4 + bq;
                int guard = 0;
                while (__hip_atomic_load(&flags[fi], __ATOMIC_RELAXED,
                                         __HIP_MEMORY_SCOPE_AGENT) < 32u) {
                    __builtin_amdgcn_s_sleep(1);
                    if (++guard > (1 << 22)) break;   // fail loud, not hung
                }
            }
            __syncthreads();
        }

        f32x4 acc[4];
        #pragma unroll
        for (int g = 0; g < 4; ++g) acc[g] = xacc[g];

        if (s > 0) {
            const f16* hrow = hx + ((((long)((s - 1) & 1) * 2 + dir) * BB) + arow) * HH;
            #pragma unroll
            for (int j = 0; j < 8; ++j) {
                const int kt = 10 + hb + j;
                const int hk = (hb + j) * 32 + kgrp;
                union { unsigned long long q[2]; f16x8 v; } uu;
                const unsigned long long* hp = (const unsigned long long*)(hrow + hk);
                uu.q[0] = __hip_atomic_load(hp,     __ATOMIC_RELAXED, __HIP_MEMORY_SCOPE_AGENT);
                uu.q[1] = __hip_atomic_load(hp + 1, __ATOMIC_RELAXED, __HIP_MEMORY_SCOPE_AGENT);
                #pragma unroll
                for (int g = 0; g < 4; ++g) {
                    const f16x8 bfr = *(const f16x8*)(Wl + (((g * 26 + kt) << 6) + lane) * 8);
                    acc[g] = __builtin_amdgcn_mfma_f32_16x16x32_f16(uu.v, bfr, acc[g], 0, 0, 0);
                }
            }
        }

        if (kh == 1) {
            #pragma unroll
            for (int g = 0; g < 4; ++g) part[bt][lane][g] = acc[g];
        }
        __syncthreads();
        if (kh == 0) {
            #pragma unroll
            for (int g = 0; g < 4; ++g) acc[g] += part[bt][lane][g];
            #pragma unroll
            for (int i = 0; i < 4; ++i) {
                const float zi = acc[0][i] + bias0;
                const float zf = acc[1][i] + bias1;
                const float zg = acc[2][i] + bias2;
                const float zo = acc[3][i] + bias3;
                cc[i] = sigmK(zf) * cc[i] + sigmK(zi) * tanhf(zg);
                hstage[bt * 16 + rbase + i][l15] = (f16)(sigmK(zo) * tanhf(cc[i]));
            }
        }
        __syncthreads();

        // cooperative coalesced hx store (64 rows x 16 u = 256 u64 chunks);
        // ONLY these stores are in the vmcnt(0) drain before the flag.
        {
            f16* hxw = hx + (((long)(s & 1) * 2 + dir) * BB) * HH;
            if (tid < 256) {
                const int row = tid >> 2, ch = tid & 3;
                union { unsigned long long q; f16 h4[4]; } pk;
                pk.h4[0] = hstage[row][ch * 4 + 0];
                pk.h4[1] = hstage[row][ch * 4 + 1];
                pk.h4[2] = hstage[row][ch * 4 + 2];
                pk.h4[3] = hstage[row][ch * 4 + 3];
                __hip_atomic_store(
                    (unsigned long long*)(hxw + (long)(b0 + row) * HH + u0 + ch * 4),
                    pk.q, __ATOMIC_RELAXED, __HIP_MEMORY_SCOPE_AGENT);
            }
            asm volatile("s_waitcnt vmcnt(0)" ::: "memory");
        }
        __syncthreads();
        if (tid == 0)
            __hip_atomic_fetch_add(&flags[(s * 2 + dir) * 4 + bq], 1u,
                                   __ATOMIC_RELAXED, __HIP_MEMORY_SCOPE_AGENT);

        // hs16 archive: OFF the critical path (after flag post), coalesced.
        // hstage stays valid until the next kh0 epilogue (>=2 barriers away).
        if (tid < 256) {
            const int row = tid >> 2, ch = tid & 3;
            union { unsigned long long q; f16 h4[4]; } pk;
            pk.h4[0] = hstage[row][ch * 4 + 0];
            pk.h4[1] = hstage[row][ch * 4 + 1];
            pk.h4[2] = hstage[row][ch * 4 + 2];
            pk.h4[3] = hstage[row][ch * 4 + 3];
            *(unsigned long long*)(hs16 + ((long)(b0 + row) * SS + s_eff) * H2
                                   + dir * HH + u0 + ch * 4) = pk.q;
        }

        // prefetch x-part for next step (independent of h; overlaps sync)
        if (s + 1 < SS) computeX(dir ? (SS - 2 - s) : (s + 1));
    }
}

// ---------------------------------------------------------------------------
// pre GEMM: block = 64 m-rows x FULL N (nt=22), grid (1, 256).
// A (hs16) fetched exactly once; ws1_16 (786 KB) is L2-resident.
// ---------------------------------------------------------------------------
__global__ __launch_bounds__(256) void k_preG(
    const f16* __restrict__ hs16, const f16* __restrict__ ws1_16,
    f16* __restrict__ pre16)
{
    const int m0 = blockIdx.x * 64;
    const int tid = threadIdx.x;
    const int wave = tid >> 6, lane = tid & 63;
    const int l15 = lane & 15;
    const int kgrp = (lane >> 4) * 8;
    const f16* Arow = hs16 + (long)(m0 + wave * 16 + l15) * H2;

    f32x4 acc[22];
    #pragma unroll
    for (int nt = 0; nt < 22; ++nt) acc[nt] = (f32x4){0.f, 0.f, 0.f, 0.f};

    for (int kt = 0; kt < 32; ++kt) {
        const int k0 = kt * 32 + kgrp;
        const f16x8 afr = *(const f16x8*)(Arow + k0);
        #pragma unroll
        for (int nt = 0; nt < 22; ++nt) {
            const f16x8 bfr = *(const f16x8*)(ws1_16 + (long)(nt * 16 + l15) * H2 + k0);
            acc[nt] = __builtin_amdgcn_mfma_f32_16x16x32_f16(afr, bfr, acc[nt], 0, 0, 0);
        }
    }

    const int rbase = (lane >> 4) * 4;
    #pragma unroll
    for (int nt = 0; nt < 22; ++nt) {
        const int n = nt * 16 + l15;
        if (n < DA) {
            #pragma unroll
            for (int i = 0; i < 4; ++i) {
                const int m = m0 + wave * 16 + rbase + i;
                pre16[(long)m * DA + n] = (f16)tanhf(acc[nt][i]);
            }
        }
    }
}

// ---------------------------------------------------------------------------
// Fused attention: logits (dot-350) + softmax, one block per batch b.
// Writes fp32 attention directly to d_out.
// ---------------------------------------------------------------------------
__global__ __launch_bounds__(256) void k_att(
    const f16* __restrict__ pre16, const float* __restrict__ ws2,
    float* __restrict__ att_out)
{
    __shared__ f16 preS[SS * DA];     // 44.8 KB
    __shared__ float w2S[RR * DA];    // 11.2 KB
    __shared__ float logS[RR * SS];   //  2 KB
    __shared__ float rmax[RR], rsum[RR];
    const int b = blockIdx.x, tid = threadIdx.x;
    {
        const unsigned long long* src =
            (const unsigned long long*)(pre16 + (long)b * SS * DA);
        unsigned long long* dst = (unsigned long long*)preS;
        for (int i = tid; i < SS * DA / 4; i += 256) dst[i] = src[i];
    }
    for (int i = tid; i < RR * DA; i += 256) w2S[i] = ws2[i];
    __syncthreads();
    for (int pp = tid; pp < RR * SS; pp += 256) {
        const int r = pp >> 6, s = pp & 63;
        const f16* prow = &preS[s * DA];
        const float* wrow = &w2S[r * DA];
        float a = 0.0f;
        for (int k = 0; k < DA; ++k) a = fmaf((float)prow[k], wrow[k], a);
        logS[r * SS + s] = a;
    }
    __syncthreads();
    if (tid < RR) {
        float mx = -1e30f;
        for (int s = 0; s < SS; ++s) mx = fmaxf(mx, logS[tid * SS + s]);
        float sm = 0.0f;
        for (int s = 0; s < SS; ++s) sm += expf(logS[tid * SS + s] - mx);
        rmax[tid] = mx; rsum[tid] = sm;
    }
    __syncthreads();
    for (int pp = tid; pp < RR * SS; pp += 256) {
        const int r = pp >> 6;
        att_out[(long)b * RR * SS + pp] = expf(logS[pp] - rmax[r]) / rsum[r];
    }
}

// sem16: one block per b; hs16 read once; acc[8][4] in registers.
__global__ __launch_bounds__(256) void k_sem(
    const float* __restrict__ att, const f16* __restrict__ hs16,
    f16* __restrict__ sem16)
{
    __shared__ float aS[RR * SS];
    const int b = blockIdx.x, tid = threadIdx.x;
    for (int i = tid; i < RR * SS; i += 256) aS[i] = att[(long)b * RR * SS + i];
    __syncthreads();
    const int d0 = tid * 4;
    float acc[RR][4] = {};
    const f16* hb = hs16 + (long)b * SS * H2;
    for (int s = 0; s < SS; ++s) {
        const f16x4 hv = *(const f16x4*)(hb + s * H2 + d0);
        const float h0 = hv[0], h1 = hv[1], h2 = hv[2], h3 = hv[3];
        #pragma unroll
        for (int r = 0; r < RR; ++r) {
            const float a = aS[r * SS + s];
            acc[r][0] = fmaf(a, h0, acc[r][0]);
            acc[r][1] = fmaf(a, h1, acc[r][1]);
            acc[r][2] = fmaf(a, h2, acc[r][2]);
            acc[r][3] = fmaf(a, h3, acc[r][3]);
        }
    }
    #pragma unroll
    for (int r = 0; r < RR; ++r) {
        f16x4 o; o[0] = (f16)acc[r][0]; o[1] = (f16)acc[r][1];
        o[2] = (f16)acc[r][2]; o[3] = (f16)acc[r][3];
        *(f16x4*)(sem16 + ((long)b * RR + r) * H2 + d0) = o;
    }
}

// ---------------------------------------------------------------------------
// pred GEMM: block = (64-n tile, r), full M=256. 8 waves x 2 m-tiles.
// ---------------------------------------------------------------------------
__global__ __launch_bounds__(512) void k_predG(
    const f16* __restrict__ sem16, const f16* __restrict__ capsT16,
    float* __restrict__ pred_out)
{
    const int n0 = blockIdx.x * 64;
    const int r  = blockIdx.y;
    const int tid = threadIdx.x;
    const int wave = tid >> 6, lane = tid & 63;
    const int l15 = lane & 15;
    const int kgrp = (lane >> 4) * 8;
    const f16* Bp = capsT16 + (long)r * 2432 * H2;
    const f16* A0 = sem16 + ((long)(wave * 32 + l15) * RR + r) * H2;

    f32x4 acc[2][4];
    #pragma unroll
    for (int mt = 0; mt < 2; ++mt)
        #pragma unroll
        for (int nt = 0; nt < 4; ++nt) acc[mt][nt] = (f32x4){0.f, 0.f, 0.f, 0.f};

    for (int kt = 0; kt < 32; ++kt) {
        const int k0 = kt * 32 + kgrp;
        const f16x8 a0 = *(const f16x8*)(A0 + k0);
        const f16x8 a1 = *(const f16x8*)(A0 + (long)16 * RR * H2 + k0);
        #pragma unroll
        for (int nt = 0; nt < 4; ++nt) {
            const f16x8 bfr = *(const f16x8*)(Bp + (long)(n0 + nt * 16 + l15) * H2 + k0);
            acc[0][nt] = __builtin_amdgcn_mfma_f32_16x16x32_f16(a0, bfr, acc[0][nt], 0, 0, 0);
            acc[1][nt] = __builtin_amdgcn_mfma_f32_16x16x32_f16(a1, bfr, acc[1][nt], 0, 0, 0);
        }
    }

    const int rbase = (lane >> 4) * 4;
    #pragma unroll
    for (int mt = 0; mt < 2; ++mt) {
        #pragma unroll
        for (int nt = 0; nt < 4; ++nt) {
            const int n = n0 + nt * 16 + l15;
            if (n < CP) {
                #pragma unroll
                for (int i = 0; i < 4; ++i) {
                    const int m = wave * 32 + mt * 16 + rbase + i;
                    pred_out[((long)m * RR + r) * CP + n] = acc[mt][nt][i];
                }
            }
        }
    }
}

// ---------------------------------------------------------------------------
// Dynamic routing (reads pred fp32 from d_out)
// ---------------------------------------------------------------------------
__global__ __launch_bounds__(256) void k_route(
    const float* __restrict__ pred,
    float* __restrict__ cls_out, float* __restrict__ routes_out)
{
    __shared__ float predS[RR * CP];
    __shared__ float logitS[RR * CC];
    __shared__ float routeS[RR * CC];
    __shared__ float preactS[CP];
    __shared__ float vS[CP];
    __shared__ float scaleS[CC];
    __shared__ float rmax[RR], rsum[RR];
    const int b = blockIdx.x, tid = threadIdx.x;
    const float* ps = pred + (long)b * RR * CP;
    for (int i = tid; i < RR * CP; i += 256) predS[i] = ps[i];
    for (int i = tid; i < RR * CC; i += 256) logitS[i] = 0.0f;
    __syncthreads();

    for (int it = 0; it < 3; ++it) {
        if (tid < RR) {
            float mx = -1e30f;
            for (int c = 0; c < CC; ++c) mx = fmaxf(mx, logitS[tid * CC + c]);
            float sm = 0.0f;
            for (int c = 0; c < CC; ++c) sm += expf(logitS[tid * CC + c] - mx);
            rmax[tid] = mx; rsum[tid] = sm;
        }
        __syncthreads();
        for (int i = tid; i < RR * CC; i += 256) {
            const int r = i / CC;
            routeS[i] = expf(logitS[i] - rmax[r]) / rsum[r];
        }
        __syncthreads();
        for (int cp = tid; cp < CP; cp += 256) {
            const int c = cp >> 4;
            float a = 0.0f;
            #pragma unroll
            for (int r = 0; r < RR; ++r)
                a = fmaf(routeS[r * CC + c], predS[r * CP + cp], a);
            preactS[cp] = a;
        }
        __syncthreads();
        for (int c = tid; c < CC; c += 256) {
            float n2 = 0.0f;
            #pragma unroll
            for (int p = 0; p < PP; ++p) { const float x = preactS[c * PP + p]; n2 = fmaf(x, x, n2); }
            scaleS[c] = (n2 / (1.0f + n2)) / sqrtf(n2 + 1e-9f);
        }
        __syncthreads();
        for (int cp = tid; cp < CP; cp += 256) vS[cp] = preactS[cp] * scaleS[cp >> 4];
        __syncthreads();
        for (int i = tid; i < RR * CC; i += 256) {
            const int r = i / CC, c = i % CC;
            float a = 0.0f;
            #pragma unroll
            for (int p = 0; p < PP; ++p)
                a = fmaf(predS[r * CP + c * PP + p], vS[c * PP + p], a);
            logitS[i] += a;
        }
        __syncthreads();
    }

    for (int i = tid; i < RR * CC; i += 256)
        routes_out[(long)b * RR * CC + i] = routeS[i];
    for (int c = tid; c < CC; c += 256) {
        float n2 = 0.0f;
        #pragma unroll
        for (int p = 0; p < PP; ++p) { const float x = vS[c * PP + p]; n2 = fmaf(x, x, n2); }
        cls_out[(long)b * CC + c] = sqrtf(n2);
    }
}

// ---------------------------------------------------------------------------
extern "C" void kernel_launch(void* const* d_in, const int* in_sizes, int n_in,
                              void* d_out, int out_size, void* d_ws, size_t ws_size,
                              hipStream_t stream)
{
    (void)in_sizes; (void)n_in; (void)out_size;
    const int*   ids   = (const int*)d_in[0];
    const float* emb   = (const float*)d_in[2];
    const float* wih_f = (const float*)d_in[3];
    const float* whh_f = (const float*)d_in[4];
    const float* bih_f = (const float*)d_in[5];
    const float* bhh_f = (const float*)d_in[6];
    const float* wih_b = (const float*)d_in[7];
    const float* whh_b = (const float*)d_in[8];
    const float* bih_b = (const float*)d_in[9];
    const float* bhh_b = (const float*)d_in[10];
    const float* ws1   = (const float*)d_in[11];
    const float* ws2   = (const float*)d_in[12];
    const float* caps  = (const float*)d_in[13];
    float* out = (float*)d_out;   // fp32 outputs

    // Workspace (word offsets); capsT16 aliases low region after k_sem.
    float* ws = (float*)d_ws;
    f16*  hs16   = (f16*)ws;                          // 8,388,608 w
    f16*  hx     = (f16*)(ws + 8388608);              //   262,144 w
    f16*  X16    = (f16*)(ws + 8650752);              // 2,621,440 w
    f16*  W16    = (f16*)(ws + 11272192);             // 1,703,936 w
    f16*  ws1_16 = (f16*)(ws + 12976128);             //   196,608 w
    f16*  sem16  = (f16*)(ws + 13172736);             // 1,048,576 w
    unsigned* flags = (unsigned*)(ws + 14221312);     //       512 w
    f16*  pre16  = X16;                               // alias (post-LSTM)
    f16*  capsT16 = (f16*)ws;                         // alias (post-sem)
    const size_t need = (size_t)(14221312 + 512) * 4;
    if (ws_size < need) return;

    // Fused staging (X16 | W16 | ws1_16 | flags)
    {
        const long total = NG_ + NW_ + NS_ + NFLAG;
        k_stage<<<(int)((total + 255) / 256), 256, 0, stream>>>(
            ids, emb, wih_f, whh_f, wih_b, whh_b, ws1, X16, W16, ws1_16, flags);
    }

    // Persistent LSTM (v5 protocol + off-path hs16 archive)
    {
        const f16* a0 = X16; f16* a1 = hs16; f16* a2 = hx; unsigned* a3 = flags;
        const f16* a4 = W16;
        const float* a5 = bih_f; const float* a6 = bhh_f;
        const float* a7 = bih_b; const float* a8 = bhh_b;
        void* kargs[] = {(void*)&a0, (void*)&a1, (void*)&a2, (void*)&a3, (void*)&a4,
                         (void*)&a5, (void*)&a6, (void*)&a7, (void*)&a8};
        hipLaunchCooperativeKernel((void*)p_lstm6, dim3(256), dim3(512),
                                   kargs, 0, stream);
    }

    // pre16 = tanh(hs16 @ ws1^T), f16 out — single-pass A fetch
    k_preG<<<dim3(256), 256, 0, stream>>>(hs16, ws1_16, pre16);

    // fused attention logits + softmax -> d_out directly
    k_att<<<BB, 256, 0, stream>>>(pre16, ws2, out + ATT_OFF);

    k_sem<<<BB, 256, 0, stream>>>(out + ATT_OFF, hs16, sem16);

    // caps -> capsT16 (hs16 region dead after k_sem)
    k_packcapsT<<<dim3(32, 76, 8), 256, 0, stream>>>(caps, capsT16);

    // pred = sem16 @ caps, fp32 out
    k_predG<<<dim3(38, 8), 512, 0, stream>>>(sem16, capsT16, out + PRED_OFF);

    k_route<<<BB, 256, 0, stream>>>(out + PRED_OFF, out + CL_OFF, out + ROUTES_OFF);
}

// Round 20
// 853.644 us; speedup vs baseline: 1.0421x; 1.0421x over previous
//
#include <hip/hip_runtime.h>
#include <hip/hip_bf16.h>
#include <hip/hip_cooperative_groups.h>
#include <math.h>

// Sizes
#define BB 256
#define SS 64
#define EE 300
#define EPX 320   // X padded
#define KP 832    // 320 + 512
#define VV 30000
#define HH 512
#define H2 1024
#define DA 350
#define RR 8
#define CC 150
#define PP 16
#define CP 2400
#define NFLAG (SS * 2 * 4)

// Output layout (elements, fp32)
#define ATT_OFF    0L
#define CL_OFF     131072L
#define PRED_OFF   169472L
#define ROUTES_OFF 5084672L

typedef _Float16 f16;
typedef f16  f16x8 __attribute__((ext_vector_type(8)));
typedef f16  f16x4 __attribute__((ext_vector_type(4)));
typedef float f32x4 __attribute__((ext_vector_type(4)));

static __device__ __forceinline__ float sigmM(float x) { return 1.0f / (1.0f + expf(-x)); }

// ---------------------------------------------------------------------------
// Fused staging: X16 gather | W16 pack | ws1_16 pack | flag zero, one kernel.
// ---------------------------------------------------------------------------
#define NG_ ((long)SS * BB * EPX)        // 5,242,880
#define NW_ ((long)2 * 2048 * KP)        // 3,407,872
#define NS_ ((long)384 * 1024)           //   393,216
__global__ __launch_bounds__(256) void m_stage(
    const int* __restrict__ ids, const float* __restrict__ emb,
    const float* __restrict__ wihF, const float* __restrict__ whhF,
    const float* __restrict__ wihB, const float* __restrict__ whhB,
    const float* __restrict__ ws1,
    f16* __restrict__ X16, f16* __restrict__ W16, f16* __restrict__ ws1_16,
    unsigned* __restrict__ flags)
{
    const long idx = (long)blockIdx.x * 256 + threadIdx.x;
    if (idx < NG_) {
        const int e = (int)(idx % EPX);
        const int row = (int)(idx / EPX);
        const int s = row >> 8, b = row & 255;
        int tok = ids[(long)b * SS + s];
        if ((unsigned)tok >= (unsigned)VV) tok = 0;
        X16[idx] = (e < EE) ? (f16)emb[(long)tok * EE + e] : (f16)0.0f;
    } else if (idx < NG_ + NW_) {
        const long i2 = idx - NG_;
        const int dir = (int)(i2 / (2048 * KP));
        const int rem = (int)(i2 % (2048 * KP));
        const int j = rem / KP, k = rem % KP;
        const float* wih = dir ? wihB : wihF;
        const float* whh = dir ? whhB : whhF;
        float v;
        if (k < EE)        v = wih[(long)j * EE + k];
        else if (k < EPX)  v = 0.0f;
        else               v = whh[(long)j * HH + (k - EPX)];
        W16[i2] = (f16)v;
    } else if (idx < NG_ + NW_ + NS_) {
        const long i3 = idx - NG_ - NW_;
        const int j = (int)(i3 >> 10);
        ws1_16[i3] = (j < DA) ? (f16)ws1[i3] : (f16)0.0f;
    } else if (idx < NG_ + NW_ + NS_ + NFLAG) {
        flags[idx - NG_ - NW_ - NS_] = 0u;
    }
}

// capsT16[r][2432][1024] transposed; rows >= 2400 zero. LDS 32x32 tiles.
__global__ __launch_bounds__(256) void m_packcapsT(
    const float* __restrict__ caps, f16* __restrict__ capsT)
{
    __shared__ float t[32][33];
    const int r = blockIdx.z, k0 = blockIdx.x * 32, n0 = blockIdx.y * 32;
    const int tx = threadIdx.x & 31, ty = threadIdx.x >> 5;
    #pragma unroll
    for (int p = 0; p < 4; ++p) {
        const int k = k0 + ty + p * 8;
        const int n = n0 + tx;
        t[ty + p * 8][tx] = (n < CP) ? caps[((long)r * H2 + k) * CP + n] : 0.0f;
    }
    __syncthreads();
    #pragma unroll
    for (int p = 0; p < 4; ++p) {
        const int n = n0 + ty + p * 8;
        if (n < 2432)
            capsT[((long)r * 2432 + n) * H2 + k0 + tx] = (f16)t[tx][ty + p * 8];
    }
}

// ---------------------------------------------------------------------------
// Persistent LSTM v7 = v6 + batched hx atomic loads (issue all 16 u64 loads
// before the MFMA chain: relaxed atomics aren't compiler-pipelined, so the
// manual split hides 15 of 16 L2 latencies). Protocol otherwise identical:
// tid0-spin + barrier release, XCD-local groups (bid&7), x-prefetch,
// off-path hs16 archive. ONE poller per block (round-16 lesson).
// ---------------------------------------------------------------------------
__global__ __launch_bounds__(512, 1) void p_lstm7(
    const f16* __restrict__ X16, f16* __restrict__ hs16,
    f16* __restrict__ hx, unsigned* __restrict__ flags,
    const f16* __restrict__ W16,
    const float* __restrict__ bihF, const float* __restrict__ bhhF,
    const float* __restrict__ bihB, const float* __restrict__ bhhB)
{
    __shared__ f16 Wl[4 * 26 * 64 * 8];   // 104 KB, fragment-ordered
    __shared__ f32x4 part[4][64][4];      // 16 KB
    __shared__ f16 hstage[64][16];        // 2 KB

    const int bid = blockIdx.x;
    const int dir = bid & 1;
    const int bq  = (bid >> 1) & 3;
    const int ut  = bid >> 3;
    const int u0  = ut * 16;
    const int b0  = bq * 64;
    const int tid = threadIdx.x;
    const int wave = tid >> 6, lane = tid & 63;
    const int bt = wave & 3, kh = wave >> 2;
    const int l15 = lane & 15;
    const int kgrp = (lane >> 4) * 8;

    // One-time weight gather into fragment order
    {
        const f16* Wsrc = W16 + (long)dir * 2048 * KP;
        for (int f = tid; f < 4 * 26 * 64; f += 512) {
            const int g  = f / (26 * 64);
            const int rm = f % (26 * 64);
            const int kt = rm >> 6, ln = rm & 63;
            const long src = ((long)g * HH + u0 + (ln & 15)) * KP + kt * 32 + ((ln >> 4) * 8);
            *(f16x8*)(Wl + (long)f * 8) = *(const f16x8*)(Wsrc + src);
        }
    }
    __syncthreads();

    const int arow = b0 + bt * 16 + l15;
    const int u = u0 + l15;
    const float* bi = dir ? bihB : bihF;
    const float* bh = dir ? bhhB : bhhF;
    const float bias0 = bi[u]          + bh[u];
    const float bias1 = bi[HH + u]     + bh[HH + u];
    const float bias2 = bi[2 * HH + u] + bh[2 * HH + u];
    const float bias3 = bi[3 * HH + u] + bh[3 * HH + u];
    const int rbase = (lane >> 4) * 4;
    float cc[4] = {0.f, 0.f, 0.f, 0.f};

    f32x4 xacc[4];
    const int xb = kh ? 5 : 0;
    auto computeX = [&](int se) {
        #pragma unroll
        for (int g = 0; g < 4; ++g) xacc[g] = (f32x4){0.f, 0.f, 0.f, 0.f};
        const f16* Xrow = X16 + ((long)se * BB + arow) * EPX;
        #pragma unroll
        for (int j = 0; j < 5; ++j) {
            const int kt = xb + j;
            const int k0 = kt * 32 + kgrp;
            const f16x8 afr = *(const f16x8*)(Xrow + k0);
            #pragma unroll
            for (int g = 0; g < 4; ++g) {
                const f16x8 bfr = *(const f16x8*)(Wl + (((g * 26 + kt) << 6) + lane) * 8);
                xacc[g] = __builtin_amdgcn_mfma_f32_16x16x32_f16(afr, bfr, xacc[g], 0, 0, 0);
            }
        }
    };
    computeX(dir ? (SS - 1) : 0);

    const int hb = kh ? 8 : 0;
    for (int s = 0; s < SS; ++s) {
        const int s_eff = dir ? (SS - 1 - s) : s;

        if (s > 0) {
            if (tid == 0) {
                const int fi = ((s - 1) * 2 + dir) * 4 + bq;
                int guard = 0;
                while (__hip_atomic_load(&flags[fi], __ATOMIC_RELAXED,
                                         __HIP_MEMORY_SCOPE_AGENT) < 32u) {
                    __builtin_amdgcn_s_sleep(1);
                    if (++guard > (1 << 22)) break;   // fail loud, not hung
                }
            }
            __syncthreads();
        }

        f32x4 acc[4];
        #pragma unroll
        for (int g = 0; g < 4; ++g) acc[g] = xacc[g];

        if (s > 0) {
            const f16* hrow = hx + ((((long)((s - 1) & 1) * 2 + dir) * BB) + arow) * HH;
            // Phase 1: issue ALL hx loads (latency overlap)
            unsigned long long q0[8], q1[8];
            #pragma unroll
            for (int j = 0; j < 8; ++j) {
                const unsigned long long* hp =
                    (const unsigned long long*)(hrow + (hb + j) * 32 + kgrp);
                q0[j] = __hip_atomic_load(hp,     __ATOMIC_RELAXED, __HIP_MEMORY_SCOPE_AGENT);
                q1[j] = __hip_atomic_load(hp + 1, __ATOMIC_RELAXED, __HIP_MEMORY_SCOPE_AGENT);
            }
            // Phase 2: MFMA chain
            #pragma unroll
            for (int j = 0; j < 8; ++j) {
                const int kt = 10 + hb + j;
                union { unsigned long long q[2]; f16x8 v; } uu;
                uu.q[0] = q0[j]; uu.q[1] = q1[j];
                #pragma unroll
                for (int g = 0; g < 4; ++g) {
                    const f16x8 bfr = *(const f16x8*)(Wl + (((g * 26 + kt) << 6) + lane) * 8);
                    acc[g] = __builtin_amdgcn_mfma_f32_16x16x32_f16(uu.v, bfr, acc[g], 0, 0, 0);
                }
            }
        }

        if (kh == 1) {
            #pragma unroll
            for (int g = 0; g < 4; ++g) part[bt][lane][g] = acc[g];
        }
        __syncthreads();
        if (kh == 0) {
            #pragma unroll
            for (int g = 0; g < 4; ++g) acc[g] += part[bt][lane][g];
            #pragma unroll
            for (int i = 0; i < 4; ++i) {
                const float zi = acc[0][i] + bias0;
                const float zf = acc[1][i] + bias1;
                const float zg = acc[2][i] + bias2;
                const float zo = acc[3][i] + bias3;
                cc[i] = sigmM(zf) * cc[i] + sigmM(zi) * tanhf(zg);
                hstage[bt * 16 + rbase + i][l15] = (f16)(sigmM(zo) * tanhf(cc[i]));
            }
        }
        __syncthreads();

        // cooperative coalesced hx store; only these are in the vmcnt drain
        {
            f16* hxw = hx + (((long)(s & 1) * 2 + dir) * BB) * HH;
            if (tid < 256) {
                const int row = tid >> 2, ch = tid & 3;
                union { unsigned long long q; f16 h4[4]; } pk;
                pk.h4[0] = hstage[row][ch * 4 + 0];
                pk.h4[1] = hstage[row][ch * 4 + 1];
                pk.h4[2] = hstage[row][ch * 4 + 2];
                pk.h4[3] = hstage[row][ch * 4 + 3];
                __hip_atomic_store(
                    (unsigned long long*)(hxw + (long)(b0 + row) * HH + u0 + ch * 4),
                    pk.q, __ATOMIC_RELAXED, __HIP_MEMORY_SCOPE_AGENT);
            }
            asm volatile("s_waitcnt vmcnt(0)" ::: "memory");
        }
        __syncthreads();
        if (tid == 0)
            __hip_atomic_fetch_add(&flags[(s * 2 + dir) * 4 + bq], 1u,
                                   __ATOMIC_RELAXED, __HIP_MEMORY_SCOPE_AGENT);

        // hs16 archive: off the critical path, coalesced from hstage
        if (tid < 256) {
            const int row = tid >> 2, ch = tid & 3;
            union { unsigned long long q; f16 h4[4]; } pk;
            pk.h4[0] = hstage[row][ch * 4 + 0];
            pk.h4[1] = hstage[row][ch * 4 + 1];
            pk.h4[2] = hstage[row][ch * 4 + 2];
            pk.h4[3] = hstage[row][ch * 4 + 3];
            *(unsigned long long*)(hs16 + ((long)(b0 + row) * SS + s_eff) * H2
                                   + dir * HH + u0 + ch * 4) = pk.q;
        }

        // prefetch x-part for next step (independent of h; overlaps sync)
        if (s + 1 < SS) computeX(dir ? (SS - 2 - s) : (s + 1));
    }
}

// ---------------------------------------------------------------------------
// pre GEMM (round-17 form, measured best): 64 m x 192 n (nt=12), grid (2,256).
// ---------------------------------------------------------------------------
__global__ __launch_bounds__(256) void m_preG(
    const f16* __restrict__ hs16, const f16* __restrict__ ws1_16,
    f16* __restrict__ pre16)
{
    const int n0 = blockIdx.x * 192;
    const int m0 = blockIdx.y * 64;
    const int tid = threadIdx.x;
    const int wave = tid >> 6, lane = tid & 63;
    const int l15 = lane & 15;
    const int kgrp = (lane >> 4) * 8;
    const f16* Arow = hs16 + (long)(m0 + wave * 16 + l15) * H2;

    f32x4 acc[12];
    #pragma unroll
    for (int nt = 0; nt < 12; ++nt) acc[nt] = (f32x4){0.f, 0.f, 0.f, 0.f};

    for (int kt = 0; kt < 32; ++kt) {
        const int k0 = kt * 32 + kgrp;
        const f16x8 afr = *(const f16x8*)(Arow + k0);
        #pragma unroll
        for (int nt = 0; nt < 12; ++nt) {
            const f16x8 bfr = *(const f16x8*)(ws1_16 + (long)(n0 + nt * 16 + l15) * H2 + k0);
            acc[nt] = __builtin_amdgcn_mfma_f32_16x16x32_f16(afr, bfr, acc[nt], 0, 0, 0);
        }
    }

    const int rbase = (lane >> 4) * 4;
    #pragma unroll
    for (int nt = 0; nt < 12; ++nt) {
        const int n = n0 + nt * 16 + l15;
        if (n < DA) {
            #pragma unroll
            for (int i = 0; i < 4; ++i) {
                const int m = m0 + wave * 16 + rbase + i;
                pre16[(long)m * DA + n] = (f16)tanhf(acc[nt][i]);
            }
        }
    }
}

// ---------------------------------------------------------------------------
// Fused attention + semantic: one block per batch b.
// logits (dot-350) -> softmax -> att to d_out + LDS -> sem from hs16.
// ---------------------------------------------------------------------------
__global__ __launch_bounds__(256) void m_attsem(
    const f16* __restrict__ pre16, const float* __restrict__ ws2,
    const f16* __restrict__ hs16,
    float* __restrict__ att_out, f16* __restrict__ sem16)
{
    __shared__ f16 preS[SS * DA];     // 44.8 KB
    __shared__ float w2S[RR * DA];    // 11.2 KB
    __shared__ float logS[RR * SS];   //  2 KB
    __shared__ float aS[RR * SS];     //  2 KB
    __shared__ float rmax[RR], rsum[RR];
    const int b = blockIdx.x, tid = threadIdx.x;
    {
        const unsigned long long* src =
            (const unsigned long long*)(pre16 + (long)b * SS * DA);
        unsigned long long* dst = (unsigned long long*)preS;
        for (int i = tid; i < SS * DA / 4; i += 256) dst[i] = src[i];
    }
    for (int i = tid; i < RR * DA; i += 256) w2S[i] = ws2[i];
    __syncthreads();
    for (int pp = tid; pp < RR * SS; pp += 256) {
        const int r = pp >> 6, s = pp & 63;
        const f16* prow = &preS[s * DA];
        const float* wrow = &w2S[r * DA];
        float a = 0.0f;
        for (int k = 0; k < DA; ++k) a = fmaf((float)prow[k], wrow[k], a);
        logS[r * SS + s] = a;
    }
    __syncthreads();
    if (tid < RR) {
        float mx = -1e30f;
        for (int s = 0; s < SS; ++s) mx = fmaxf(mx, logS[tid * SS + s]);
        float sm = 0.0f;
        for (int s = 0; s < SS; ++s) sm += expf(logS[tid * SS + s] - mx);
        rmax[tid] = mx; rsum[tid] = sm;
    }
    __syncthreads();
    for (int pp = tid; pp < RR * SS; pp += 256) {
        const int r = pp >> 6;
        const float v = expf(logS[pp] - rmax[r]) / rsum[r];
        att_out[(long)b * RR * SS + pp] = v;
        aS[pp] = v;
    }
    __syncthreads();

    // semantic: thread owns 4 contiguous d; hs16 row reads coalesced
    const int d0 = tid * 4;
    float acc[RR][4] = {};
    const f16* hb = hs16 + (long)b * SS * H2;
    for (int s = 0; s < SS; ++s) {
        const f16x4 hv = *(const f16x4*)(hb + s * H2 + d0);
        const float h0 = hv[0], h1 = hv[1], h2 = hv[2], h3 = hv[3];
        #pragma unroll
        for (int r = 0; r < RR; ++r) {
            const float a = aS[r * SS + s];
            acc[r][0] = fmaf(a, h0, acc[r][0]);
            acc[r][1] = fmaf(a, h1, acc[r][1]);
            acc[r][2] = fmaf(a, h2, acc[r][2]);
            acc[r][3] = fmaf(a, h3, acc[r][3]);
        }
    }
    #pragma unroll
    for (int r = 0; r < RR; ++r) {
        f16x4 o; o[0] = (f16)acc[r][0]; o[1] = (f16)acc[r][1];
        o[2] = (f16)acc[r][2]; o[3] = (f16)acc[r][3];
        *(f16x4*)(sem16 + ((long)b * RR + r) * H2 + d0) = o;
    }
}

// ---------------------------------------------------------------------------
// pred GEMM: block = (64-n tile, r), full M=256. 8 waves x 2 m-tiles.
// ---------------------------------------------------------------------------
__global__ __launch_bounds__(512) void m_predG(
    const f16* __restrict__ sem16, const f16* __restrict__ capsT16,
    float* __restrict__ pred_out)
{
    const int n0 = blockIdx.x * 64;
    const int r  = blockIdx.y;
    const int tid = threadIdx.x;
    const int wave = tid >> 6, lane = tid & 63;
    const int l15 = lane & 15;
    const int kgrp = (lane >> 4) * 8;
    const f16* Bp = capsT16 + (long)r * 2432 * H2;
    const f16* A0 = sem16 + ((long)(wave * 32 + l15) * RR + r) * H2;

    f32x4 acc[2][4];
    #pragma unroll
    for (int mt = 0; mt < 2; ++mt)
        #pragma unroll
        for (int nt = 0; nt < 4; ++nt) acc[mt][nt] = (f32x4){0.f, 0.f, 0.f, 0.f};

    for (int kt = 0; kt < 32; ++kt) {
        const int k0 = kt * 32 + kgrp;
        const f16x8 a0 = *(const f16x8*)(A0 + k0);
        const f16x8 a1 = *(const f16x8*)(A0 + (long)16 * RR * H2 + k0);
        #pragma unroll
        for (int nt = 0; nt < 4; ++nt) {
            const f16x8 bfr = *(const f16x8*)(Bp + (long)(n0 + nt * 16 + l15) * H2 + k0);
            acc[0][nt] = __builtin_amdgcn_mfma_f32_16x16x32_f16(a0, bfr, acc[0][nt], 0, 0, 0);
            acc[1][nt] = __builtin_amdgcn_mfma_f32_16x16x32_f16(a1, bfr, acc[1][nt], 0, 0, 0);
        }
    }

    const int rbase = (lane >> 4) * 4;
    #pragma unroll
    for (int mt = 0; mt < 2; ++mt) {
        #pragma unroll
        for (int nt = 0; nt < 4; ++nt) {
            const int n = n0 + nt * 16 + l15;
            if (n < CP) {
                #pragma unroll
                for (int i = 0; i < 4; ++i) {
                    const int m = wave * 32 + mt * 16 + rbase + i;
                    pred_out[((long)m * RR + r) * CP + n] = acc[mt][nt][i];
                }
            }
        }
    }
}

// ---------------------------------------------------------------------------
// Dynamic routing, 512 threads (halved serial-phase time vs 256).
// ---------------------------------------------------------------------------
__global__ __launch_bounds__(512) void m_route(
    const float* __restrict__ pred,
    float* __restrict__ cls_out, float* __restrict__ routes_out)
{
    __shared__ float predS[RR * CP];
    __shared__ float logitS[RR * CC];
    __shared__ float routeS[RR * CC];
    __shared__ float preactS[CP];
    __shared__ float vS[CP];
    __shared__ float scaleS[CC];
    __shared__ float rmax[RR], rsum[RR];
    const int b = blockIdx.x, tid = threadIdx.x;
    const float* ps = pred + (long)b * RR * CP;
    for (int i = tid; i < RR * CP; i += 512) predS[i] = ps[i];
    for (int i = tid; i < RR * CC; i += 512) logitS[i] = 0.0f;
    __syncthreads();

    for (int it = 0; it < 3; ++it) {
        if (tid < RR) {
            float mx = -1e30f;
            for (int c = 0; c < CC; ++c) mx = fmaxf(mx, logitS[tid * CC + c]);
            float sm = 0.0f;
            for (int c = 0; c < CC; ++c) sm += expf(logitS[tid * CC + c] - mx);
            rmax[tid] = mx; rsum[tid] = sm;
        }
        __syncthreads();
        for (int i = tid; i < RR * CC; i += 512) {
            const int r = i / CC;
            routeS[i] = expf(logitS[i] - rmax[r]) / rsum[r];
        }
        __syncthreads();
        for (int cp = tid; cp < CP; cp += 512) {
            const int c = cp >> 4;
            float a = 0.0f;
            #pragma unroll
            for (int r = 0; r < RR; ++r)
                a = fmaf(routeS[r * CC + c], predS[r * CP + cp], a);
            preactS[cp] = a;
        }
        __syncthreads();
        for (int c = tid; c < CC; c += 512) {
            float n2 = 0.0f;
            #pragma unroll
            for (int p = 0; p < PP; ++p) { const float x = preactS[c * PP + p]; n2 = fmaf(x, x, n2); }
            scaleS[c] = (n2 / (1.0f + n2)) / sqrtf(n2 + 1e-9f);
        }
        __syncthreads();
        for (int cp = tid; cp < CP; cp += 512) vS[cp] = preactS[cp] * scaleS[cp >> 4];
        __syncthreads();
        for (int i = tid; i < RR * CC; i += 512) {
            const int r = i / CC, c = i % CC;
            float a = 0.0f;
            #pragma unroll
            for (int p = 0; p < PP; ++p)
                a = fmaf(predS[r * CP + c * PP + p], vS[c * PP + p], a);
            logitS[i] += a;
        }
        __syncthreads();
    }

    for (int i = tid; i < RR * CC; i += 512)
        routes_out[(long)b * RR * CC + i] = routeS[i];
    for (int c = tid; c < CC; c += 512) {
        float n2 = 0.0f;
        #pragma unroll
        for (int p = 0; p < PP; ++p) { const float x = vS[c * PP + p]; n2 = fmaf(x, x, n2); }
        cls_out[(long)b * CC + c] = sqrtf(n2);
    }
}

// ---------------------------------------------------------------------------
extern "C" void kernel_launch(void* const* d_in, const int* in_sizes, int n_in,
                              void* d_out, int out_size, void* d_ws, size_t ws_size,
                              hipStream_t stream)
{
    (void)in_sizes; (void)n_in; (void)out_size;
    const int*   ids   = (const int*)d_in[0];
    const float* emb   = (const float*)d_in[2];
    const float* wih_f = (const float*)d_in[3];
    const float* whh_f = (const float*)d_in[4];
    const float* bih_f = (const float*)d_in[5];
    const float* bhh_f = (const float*)d_in[6];
    const float* wih_b = (const float*)d_in[7];
    const float* whh_b = (const float*)d_in[8];
    const float* bih_b = (const float*)d_in[9];
    const float* bhh_b = (const float*)d_in[10];
    const float* ws1   = (const float*)d_in[11];
    const float* ws2   = (const float*)d_in[12];
    const float* caps  = (const float*)d_in[13];
    float* out = (float*)d_out;   // fp32 outputs

    // Workspace (word offsets); capsT16 aliases low region after m_attsem.
    float* ws = (float*)d_ws;
    f16*  hs16   = (f16*)ws;                          // 8,388,608 w
    f16*  hx     = (f16*)(ws + 8388608);              //   262,144 w
    f16*  X16    = (f16*)(ws + 8650752);              // 2,621,440 w
    f16*  W16    = (f16*)(ws + 11272192);             // 1,703,936 w
    f16*  ws1_16 = (f16*)(ws + 12976128);             //   196,608 w
    f16*  sem16  = (f16*)(ws + 13172736);             // 1,048,576 w
    unsigned* flags = (unsigned*)(ws + 14221312);     //       512 w
    f16*  pre16  = X16;                               // alias (post-LSTM)
    f16*  capsT16 = (f16*)ws;                         // alias (post-attsem)
    const size_t need = (size_t)(14221312 + 512) * 4;
    if (ws_size < need) return;

    // Fused staging (X16 | W16 | ws1_16 | flags)
    {
        const long total = NG_ + NW_ + NS_ + NFLAG;
        m_stage<<<(int)((total + 255) / 256), 256, 0, stream>>>(
            ids, emb, wih_f, whh_f, wih_b, whh_b, ws1, X16, W16, ws1_16, flags);
    }

    // Persistent LSTM (v7: batched hx loads)
    {
        const f16* a0 = X16; f16* a1 = hs16; f16* a2 = hx; unsigned* a3 = flags;
        const f16* a4 = W16;
        const float* a5 = bih_f; const float* a6 = bhh_f;
        const float* a7 = bih_b; const float* a8 = bhh_b;
        void* kargs[] = {(void*)&a0, (void*)&a1, (void*)&a2, (void*)&a3, (void*)&a4,
                         (void*)&a5, (void*)&a6, (void*)&a7, (void*)&a8};
        hipLaunchCooperativeKernel((void*)p_lstm7, dim3(256), dim3(512),
                                   kargs, 0, stream);
    }

    // pre16 = tanh(hs16 @ ws1^T), f16 out
    m_preG<<<dim3(2, 256), 256, 0, stream>>>(hs16, ws1_16, pre16);

    // fused attention + semantic (att -> d_out, sem -> sem16)
    m_attsem<<<BB, 256, 0, stream>>>(pre16, ws2, hs16, out + ATT_OFF, sem16);

    // caps -> capsT16 (hs16 region dead after m_attsem)
    m_packcapsT<<<dim3(32, 76, 8), 256, 0, stream>>>(caps, capsT16);

    // pred = sem16 @ caps, fp32 out
    m_predG<<<dim3(38, 8), 512, 0, stream>>>(sem16, capsT16, out + PRED_OFF);

    m_route<<<BB, 512, 0, stream>>>(out + PRED_OFF, out + CL_OFF, out + ROUTES_OFF);
}

// Round 21
// 782.434 us; speedup vs baseline: 1.1370x; 1.0910x over previous
//
#include <hip/hip_runtime.h>
#include <hip/hip_bf16.h>
#include <hip/hip_cooperative_groups.h>
#include <math.h>

// Sizes
#define BB 256
#define SS 64
#define EE 300
#define EPX 320   // X padded
#define KP 832    // 320 + 512
#define VV 30000
#define HH 512
#define H2 1024
#define DA 350
#define RR 8
#define CC 150
#define PP 16
#define CP 2400
#define NPF 4096  // per-producer flags: 256 blocks x 16 u32 (64B padded lines)

// Output layout (elements, fp32)
#define ATT_OFF    0L
#define CL_OFF     131072L
#define PRED_OFF   169472L
#define ROUTES_OFF 5084672L

typedef _Float16 f16;
typedef f16  f16x8 __attribute__((ext_vector_type(8)));
typedef f16  f16x4 __attribute__((ext_vector_type(4)));
typedef float f32x4 __attribute__((ext_vector_type(4)));

static __device__ __forceinline__ float sigmN(float x) { return 1.0f / (1.0f + expf(-x)); }

// ---------------------------------------------------------------------------
// Fused staging: X16 gather | W16 pack | ws1_16 pack | pflag zero.
// ---------------------------------------------------------------------------
#define NG_ ((long)SS * BB * EPX)        // 5,242,880
#define NW_ ((long)2 * 2048 * KP)        // 3,407,872
#define NS_ ((long)384 * 1024)           //   393,216
__global__ __launch_bounds__(256) void n_stage(
    const int* __restrict__ ids, const float* __restrict__ emb,
    const float* __restrict__ wihF, const float* __restrict__ whhF,
    const float* __restrict__ wihB, const float* __restrict__ whhB,
    const float* __restrict__ ws1,
    f16* __restrict__ X16, f16* __restrict__ W16, f16* __restrict__ ws1_16,
    unsigned* __restrict__ pflag)
{
    const long idx = (long)blockIdx.x * 256 + threadIdx.x;
    if (idx < NG_) {
        const int e = (int)(idx % EPX);
        const int row = (int)(idx / EPX);
        const int s = row >> 8, b = row & 255;
        int tok = ids[(long)b * SS + s];
        if ((unsigned)tok >= (unsigned)VV) tok = 0;
        X16[idx] = (e < EE) ? (f16)emb[(long)tok * EE + e] : (f16)0.0f;
    } else if (idx < NG_ + NW_) {
        const long i2 = idx - NG_;
        const int dir = (int)(i2 / (2048 * KP));
        const int rem = (int)(i2 % (2048 * KP));
        const int j = rem / KP, k = rem % KP;
        const float* wih = dir ? wihB : wihF;
        const float* whh = dir ? whhB : whhF;
        float v;
        if (k < EE)        v = wih[(long)j * EE + k];
        else if (k < EPX)  v = 0.0f;
        else               v = whh[(long)j * HH + (k - EPX)];
        W16[i2] = (f16)v;
    } else if (idx < NG_ + NW_ + NS_) {
        const long i3 = idx - NG_ - NW_;
        const int j = (int)(i3 >> 10);
        ws1_16[i3] = (j < DA) ? (f16)ws1[i3] : (f16)0.0f;
    } else if (idx < NG_ + NW_ + NS_ + NPF) {
        pflag[idx - NG_ - NW_ - NS_] = 0u;
    }
}

// capsT16[r][2432][1024] transposed; rows >= 2400 zero. LDS 32x32 tiles.
__global__ __launch_bounds__(256) void n_packcapsT(
    const float* __restrict__ caps, f16* __restrict__ capsT)
{
    __shared__ float t[32][33];
    const int r = blockIdx.z, k0 = blockIdx.x * 32, n0 = blockIdx.y * 32;
    const int tx = threadIdx.x & 31, ty = threadIdx.x >> 5;
    #pragma unroll
    for (int p = 0; p < 4; ++p) {
        const int k = k0 + ty + p * 8;
        const int n = n0 + tx;
        t[ty + p * 8][tx] = (n < CP) ? caps[((long)r * H2 + k) * CP + n] : 0.0f;
    }
    __syncthreads();
    #pragma unroll
    for (int p = 0; p < 4; ++p) {
        const int n = n0 + ty + p * 8;
        if (n < 2432)
            capsT[((long)r * 2432 + n) * H2 + k0 + tx] = (f16)t[tx][ty + p * 8];
    }
}

// ---------------------------------------------------------------------------
// Persistent LSTM v8. Protocol changes vs v6/v7 (both measured ~570 us):
//  (1) per-producer flag slots: each block owns a padded 64B line holding a
//      monotonic "completed step+1" counter, written with atomic STORE (no
//      RMW hotline; 32 parallel lines instead of 1 serialized cacheline).
//  (2) wave-parallel detection: wave 0 lanes 0..31 poll the 32 producer
//      lines of this group; __all(v>=s) then ONE block barrier releases
//      (keeps round-16 "one polling wave" fan-in invariant).
//  (3) part buffer re-laid as [bt][g][lane] -> lane-stride 16B, bank-
//      conflict-free (was 32-way, 9.9M conflict cycles).
// Everything else identical to v6: XCD-local groups (bid&7), x-prefetch,
// off-path hs16 archive, interleaved h loads, c in registers.
// ---------------------------------------------------------------------------
__global__ __launch_bounds__(512, 1) void p_lstm8(
    const f16* __restrict__ X16, f16* __restrict__ hs16,
    f16* __restrict__ hx, unsigned* __restrict__ pflag,
    const f16* __restrict__ W16,
    const float* __restrict__ bihF, const float* __restrict__ bhhF,
    const float* __restrict__ bihB, const float* __restrict__ bhhB)
{
    __shared__ f16 Wl[4 * 26 * 64 * 8];   // 104 KB, fragment-ordered
    __shared__ f32x4 part[4][4][64];      // 16 KB, [bt][g][lane]: conflict-free
    __shared__ f16 hstage[64][16];        // 2 KB

    const int bid = blockIdx.x;
    const int dir = bid & 1;
    const int bq  = (bid >> 1) & 3;
    const int ut  = bid >> 3;
    const int u0  = ut * 16;
    const int b0  = bq * 64;
    const int tid = threadIdx.x;
    const int wave = tid >> 6, lane = tid & 63;
    const int bt = wave & 3, kh = wave >> 2;
    const int l15 = lane & 15;
    const int kgrp = (lane >> 4) * 8;
    const int grp32 = (dir * 4 + bq) * 32;          // group base in block-index space
    unsigned* myflag = pflag + (grp32 + ut) * 16;   // own padded line

    // One-time weight gather into fragment order
    {
        const f16* Wsrc = W16 + (long)dir * 2048 * KP;
        for (int f = tid; f < 4 * 26 * 64; f += 512) {
            const int g  = f / (26 * 64);
            const int rm = f % (26 * 64);
            const int kt = rm >> 6, ln = rm & 63;
            const long src = ((long)g * HH + u0 + (ln & 15)) * KP + kt * 32 + ((ln >> 4) * 8);
            *(f16x8*)(Wl + (long)f * 8) = *(const f16x8*)(Wsrc + src);
        }
    }
    __syncthreads();

    const int arow = b0 + bt * 16 + l15;
    const int u = u0 + l15;
    const float* bi = dir ? bihB : bihF;
    const float* bh = dir ? bhhB : bhhF;
    const float bias0 = bi[u]          + bh[u];
    const float bias1 = bi[HH + u]     + bh[HH + u];
    const float bias2 = bi[2 * HH + u] + bh[2 * HH + u];
    const float bias3 = bi[3 * HH + u] + bh[3 * HH + u];
    const int rbase = (lane >> 4) * 4;
    float cc[4] = {0.f, 0.f, 0.f, 0.f};

    f32x4 xacc[4];
    const int xb = kh ? 5 : 0;
    auto computeX = [&](int se) {
        #pragma unroll
        for (int g = 0; g < 4; ++g) xacc[g] = (f32x4){0.f, 0.f, 0.f, 0.f};
        const f16* Xrow = X16 + ((long)se * BB + arow) * EPX;
        #pragma unroll
        for (int j = 0; j < 5; ++j) {
            const int kt = xb + j;
            const int k0 = kt * 32 + kgrp;
            const f16x8 afr = *(const f16x8*)(Xrow + k0);
            #pragma unroll
            for (int g = 0; g < 4; ++g) {
                const f16x8 bfr = *(const f16x8*)(Wl + (((g * 26 + kt) << 6) + lane) * 8);
                xacc[g] = __builtin_amdgcn_mfma_f32_16x16x32_f16(afr, bfr, xacc[g], 0, 0, 0);
            }
        }
    };
    computeX(dir ? (SS - 1) : 0);

    const int hb = kh ? 8 : 0;
    for (int s = 0; s < SS; ++s) {
        const int s_eff = dir ? (SS - 1 - s) : s;

        // wave-parallel group wait: wave 0 lanes poll 32 distinct lines
        if (s > 0) {
            if (wave == 0) {
                const unsigned* fp = pflag + (grp32 + (lane & 31)) * 16;
                int guard = 0;
                unsigned v = __hip_atomic_load(fp, __ATOMIC_RELAXED,
                                               __HIP_MEMORY_SCOPE_AGENT);
                while (!__all((int)(v >= (unsigned)s))) {
                    __builtin_amdgcn_s_sleep(1);
                    v = __hip_atomic_load(fp, __ATOMIC_RELAXED,
                                          __HIP_MEMORY_SCOPE_AGENT);
                    if (++guard > (1 << 22)) break;   // fail loud, not hung
                }
            }
            __syncthreads();
        }

        f32x4 acc[4];
        #pragma unroll
        for (int g = 0; g < 4; ++g) acc[g] = xacc[g];

        if (s > 0) {
            const f16* hrow = hx + ((((long)((s - 1) & 1) * 2 + dir) * BB) + arow) * HH;
            #pragma unroll
            for (int j = 0; j < 8; ++j) {
                const int kt = 10 + hb + j;
                const int hk = (hb + j) * 32 + kgrp;
                union { unsigned long long q[2]; f16x8 v; } uu;
                const unsigned long long* hp = (const unsigned long long*)(hrow + hk);
                uu.q[0] = __hip_atomic_load(hp,     __ATOMIC_RELAXED, __HIP_MEMORY_SCOPE_AGENT);
                uu.q[1] = __hip_atomic_load(hp + 1, __ATOMIC_RELAXED, __HIP_MEMORY_SCOPE_AGENT);
                #pragma unroll
                for (int g = 0; g < 4; ++g) {
                    const f16x8 bfr = *(const f16x8*)(Wl + (((g * 26 + kt) << 6) + lane) * 8);
                    acc[g] = __builtin_amdgcn_mfma_f32_16x16x32_f16(uu.v, bfr, acc[g], 0, 0, 0);
                }
            }
        }

        if (kh == 1) {
            #pragma unroll
            for (int g = 0; g < 4; ++g) part[bt][g][lane] = acc[g];
        }
        __syncthreads();
        if (kh == 0) {
            #pragma unroll
            for (int g = 0; g < 4; ++g) acc[g] += part[bt][g][lane];
            #pragma unroll
            for (int i = 0; i < 4; ++i) {
                const float zi = acc[0][i] + bias0;
                const float zf = acc[1][i] + bias1;
                const float zg = acc[2][i] + bias2;
                const float zo = acc[3][i] + bias3;
                cc[i] = sigmN(zf) * cc[i] + sigmN(zi) * tanhf(zg);
                hstage[bt * 16 + rbase + i][l15] = (f16)(sigmN(zo) * tanhf(cc[i]));
            }
        }
        __syncthreads();

        // cooperative coalesced hx store; only these are in the vmcnt drain
        {
            f16* hxw = hx + (((long)(s & 1) * 2 + dir) * BB) * HH;
            if (tid < 256) {
                const int row = tid >> 2, ch = tid & 3;
                union { unsigned long long q; f16 h4[4]; } pk;
                pk.h4[0] = hstage[row][ch * 4 + 0];
                pk.h4[1] = hstage[row][ch * 4 + 1];
                pk.h4[2] = hstage[row][ch * 4 + 2];
                pk.h4[3] = hstage[row][ch * 4 + 3];
                __hip_atomic_store(
                    (unsigned long long*)(hxw + (long)(b0 + row) * HH + u0 + ch * 4),
                    pk.q, __ATOMIC_RELAXED, __HIP_MEMORY_SCOPE_AGENT);
            }
            asm volatile("s_waitcnt vmcnt(0)" ::: "memory");
        }
        __syncthreads();
        // per-producer flag: plain atomic store on own padded line (no RMW)
        if (tid == 0)
            __hip_atomic_store(myflag, (unsigned)(s + 1),
                               __ATOMIC_RELAXED, __HIP_MEMORY_SCOPE_AGENT);

        // hs16 archive: off the critical path, coalesced from hstage
        if (tid < 256) {
            const int row = tid >> 2, ch = tid & 3;
            union { unsigned long long q; f16 h4[4]; } pk;
            pk.h4[0] = hstage[row][ch * 4 + 0];
            pk.h4[1] = hstage[row][ch * 4 + 1];
            pk.h4[2] = hstage[row][ch * 4 + 2];
            pk.h4[3] = hstage[row][ch * 4 + 3];
            *(unsigned long long*)(hs16 + ((long)(b0 + row) * SS + s_eff) * H2
                                   + dir * HH + u0 + ch * 4) = pk.q;
        }

        // prefetch x-part for next step (independent of h; overlaps sync)
        if (s + 1 < SS) computeX(dir ? (SS - 2 - s) : (s + 1));
    }
}

// ---------------------------------------------------------------------------
// pre GEMM (measured best): 64 m x 192 n (nt=12), grid (2, 256).
// ---------------------------------------------------------------------------
__global__ __launch_bounds__(256) void n_preG(
    const f16* __restrict__ hs16, const f16* __restrict__ ws1_16,
    f16* __restrict__ pre16)
{
    const int n0 = blockIdx.x * 192;
    const int m0 = blockIdx.y * 64;
    const int tid = threadIdx.x;
    const int wave = tid >> 6, lane = tid & 63;
    const int l15 = lane & 15;
    const int kgrp = (lane >> 4) * 8;
    const f16* Arow = hs16 + (long)(m0 + wave * 16 + l15) * H2;

    f32x4 acc[12];
    #pragma unroll
    for (int nt = 0; nt < 12; ++nt) acc[nt] = (f32x4){0.f, 0.f, 0.f, 0.f};

    for (int kt = 0; kt < 32; ++kt) {
        const int k0 = kt * 32 + kgrp;
        const f16x8 afr = *(const f16x8*)(Arow + k0);
        #pragma unroll
        for (int nt = 0; nt < 12; ++nt) {
            const f16x8 bfr = *(const f16x8*)(ws1_16 + (long)(n0 + nt * 16 + l15) * H2 + k0);
            acc[nt] = __builtin_amdgcn_mfma_f32_16x16x32_f16(afr, bfr, acc[nt], 0, 0, 0);
        }
    }

    const int rbase = (lane >> 4) * 4;
    #pragma unroll
    for (int nt = 0; nt < 12; ++nt) {
        const int n = n0 + nt * 16 + l15;
        if (n < DA) {
            #pragma unroll
            for (int i = 0; i < 4; ++i) {
                const int m = m0 + wave * 16 + rbase + i;
                pre16[(long)m * DA + n] = (f16)tanhf(acc[nt][i]);
            }
        }
    }
}

// ---------------------------------------------------------------------------
// Fused attention + semantic: one block per batch b.
// ---------------------------------------------------------------------------
__global__ __launch_bounds__(256) void n_attsem(
    const f16* __restrict__ pre16, const float* __restrict__ ws2,
    const f16* __restrict__ hs16,
    float* __restrict__ att_out, f16* __restrict__ sem16)
{
    __shared__ f16 preS[SS * DA];     // 44.8 KB
    __shared__ float w2S[RR * DA];    // 11.2 KB
    __shared__ float logS[RR * SS];   //  2 KB
    __shared__ float aS[RR * SS];     //  2 KB
    __shared__ float rmax[RR], rsum[RR];
    const int b = blockIdx.x, tid = threadIdx.x;
    {
        const unsigned long long* src =
            (const unsigned long long*)(pre16 + (long)b * SS * DA);
        unsigned long long* dst = (unsigned long long*)preS;
        for (int i = tid; i < SS * DA / 4; i += 256) dst[i] = src[i];
    }
    for (int i = tid; i < RR * DA; i += 256) w2S[i] = ws2[i];
    __syncthreads();
    for (int pp = tid; pp < RR * SS; pp += 256) {
        const int r = pp >> 6, s = pp & 63;
        const f16* prow = &preS[s * DA];
        const float* wrow = &w2S[r * DA];
        float a = 0.0f;
        for (int k = 0; k < DA; ++k) a = fmaf((float)prow[k], wrow[k], a);
        logS[r * SS + s] = a;
    }
    __syncthreads();
    if (tid < RR) {
        float mx = -1e30f;
        for (int s = 0; s < SS; ++s) mx = fmaxf(mx, logS[tid * SS + s]);
        float sm = 0.0f;
        for (int s = 0; s < SS; ++s) sm += expf(logS[tid * SS + s] - mx);
        rmax[tid] = mx; rsum[tid] = sm;
    }
    __syncthreads();
    for (int pp = tid; pp < RR * SS; pp += 256) {
        const int r = pp >> 6;
        const float v = expf(logS[pp] - rmax[r]) / rsum[r];
        att_out[(long)b * RR * SS + pp] = v;
        aS[pp] = v;
    }
    __syncthreads();

    const int d0 = tid * 4;
    float acc[RR][4] = {};
    const f16* hb = hs16 + (long)b * SS * H2;
    for (int s = 0; s < SS; ++s) {
        const f16x4 hv = *(const f16x4*)(hb + s * H2 + d0);
        const float h0 = hv[0], h1 = hv[1], h2 = hv[2], h3 = hv[3];
        #pragma unroll
        for (int r = 0; r < RR; ++r) {
            const float a = aS[r * SS + s];
            acc[r][0] = fmaf(a, h0, acc[r][0]);
            acc[r][1] = fmaf(a, h1, acc[r][1]);
            acc[r][2] = fmaf(a, h2, acc[r][2]);
            acc[r][3] = fmaf(a, h3, acc[r][3]);
        }
    }
    #pragma unroll
    for (int r = 0; r < RR; ++r) {
        f16x4 o; o[0] = (f16)acc[r][0]; o[1] = (f16)acc[r][1];
        o[2] = (f16)acc[r][2]; o[3] = (f16)acc[r][3];
        *(f16x4*)(sem16 + ((long)b * RR + r) * H2 + d0) = o;
    }
}

// ---------------------------------------------------------------------------
// pred GEMM: block = (64-n tile, r), full M=256. 8 waves x 2 m-tiles.
// ---------------------------------------------------------------------------
__global__ __launch_bounds__(512) void n_predG(
    const f16* __restrict__ sem16, const f16* __restrict__ capsT16,
    float* __restrict__ pred_out)
{
    const int n0 = blockIdx.x * 64;
    const int r  = blockIdx.y;
    const int tid = threadIdx.x;
    const int wave = tid >> 6, lane = tid & 63;
    const int l15 = lane & 15;
    const int kgrp = (lane >> 4) * 8;
    const f16* Bp = capsT16 + (long)r * 2432 * H2;
    const f16* A0 = sem16 + ((long)(wave * 32 + l15) * RR + r) * H2;

    f32x4 acc[2][4];
    #pragma unroll
    for (int mt = 0; mt < 2; ++mt)
        #pragma unroll
        for (int nt = 0; nt < 4; ++nt) acc[mt][nt] = (f32x4){0.f, 0.f, 0.f, 0.f};

    for (int kt = 0; kt < 32; ++kt) {
        const int k0 = kt * 32 + kgrp;
        const f16x8 a0 = *(const f16x8*)(A0 + k0);
        const f16x8 a1 = *(const f16x8*)(A0 + (long)16 * RR * H2 + k0);
        #pragma unroll
        for (int nt = 0; nt < 4; ++nt) {
            const f16x8 bfr = *(const f16x8*)(Bp + (long)(n0 + nt * 16 + l15) * H2 + k0);
            acc[0][nt] = __builtin_amdgcn_mfma_f32_16x16x32_f16(a0, bfr, acc[0][nt], 0, 0, 0);
            acc[1][nt] = __builtin_amdgcn_mfma_f32_16x16x32_f16(a1, bfr, acc[1][nt], 0, 0, 0);
        }
    }

    const int rbase = (lane >> 4) * 4;
    #pragma unroll
    for (int mt = 0; mt < 2; ++mt) {
        #pragma unroll
        for (int nt = 0; nt < 4; ++nt) {
            const int n = n0 + nt * 16 + l15;
            if (n < CP) {
                #pragma unroll
                for (int i = 0; i < 4; ++i) {
                    const int m = wave * 32 + mt * 16 + rbase + i;
                    pred_out[((long)m * RR + r) * CP + n] = acc[mt][nt][i];
                }
            }
        }
    }
}

// ---------------------------------------------------------------------------
// Dynamic routing, 512 threads.
// ---------------------------------------------------------------------------
__global__ __launch_bounds__(512) void n_route(
    const float* __restrict__ pred,
    float* __restrict__ cls_out, float* __restrict__ routes_out)
{
    __shared__ float predS[RR * CP];
    __shared__ float logitS[RR * CC];
    __shared__ float routeS[RR * CC];
    __shared__ float preactS[CP];
    __shared__ float vS[CP];
    __shared__ float scaleS[CC];
    __shared__ float rmax[RR], rsum[RR];
    const int b = blockIdx.x, tid = threadIdx.x;
    const float* ps = pred + (long)b * RR * CP;
    for (int i = tid; i < RR * CP; i += 512) predS[i] = ps[i];
    for (int i = tid; i < RR * CC; i += 512) logitS[i] = 0.0f;
    __syncthreads();

    for (int it = 0; it < 3; ++it) {
        if (tid < RR) {
            float mx = -1e30f;
            for (int c = 0; c < CC; ++c) mx = fmaxf(mx, logitS[tid * CC + c]);
            float sm = 0.0f;
            for (int c = 0; c < CC; ++c) sm += expf(logitS[tid * CC + c] - mx);
            rmax[tid] = mx; rsum[tid] = sm;
        }
        __syncthreads();
        for (int i = tid; i < RR * CC; i += 512) {
            const int r = i / CC;
            routeS[i] = expf(logitS[i] - rmax[r]) / rsum[r];
        }
        __syncthreads();
        for (int cp = tid; cp < CP; cp += 512) {
            const int c = cp >> 4;
            float a = 0.0f;
            #pragma unroll
            for (int r = 0; r < RR; ++r)
                a = fmaf(routeS[r * CC + c], predS[r * CP + cp], a);
            preactS[cp] = a;
        }
        __syncthreads();
        for (int c = tid; c < CC; c += 512) {
            float n2 = 0.0f;
            #pragma unroll
            for (int p = 0; p < PP; ++p) { const float x = preactS[c * PP + p]; n2 = fmaf(x, x, n2); }
            scaleS[c] = (n2 / (1.0f + n2)) / sqrtf(n2 + 1e-9f);
        }
        __syncthreads();
        for (int cp = tid; cp < CP; cp += 512) vS[cp] = preactS[cp] * scaleS[cp >> 4];
        __syncthreads();
        for (int i = tid; i < RR * CC; i += 512) {
            const int r = i / CC, c = i % CC;
            float a = 0.0f;
            #pragma unroll
            for (int p = 0; p < PP; ++p)
                a = fmaf(predS[r * CP + c * PP + p], vS[c * PP + p], a);
            logitS[i] += a;
        }
        __syncthreads();
    }

    for (int i = tid; i < RR * CC; i += 512)
        routes_out[(long)b * RR * CC + i] = routeS[i];
    for (int c = tid; c < CC; c += 512) {
        float n2 = 0.0f;
        #pragma unroll
        for (int p = 0; p < PP; ++p) { const float x = vS[c * PP + p]; n2 = fmaf(x, x, n2); }
        cls_out[(long)b * CC + c] = sqrtf(n2);
    }
}

// ---------------------------------------------------------------------------
extern "C" void kernel_launch(void* const* d_in, const int* in_sizes, int n_in,
                              void* d_out, int out_size, void* d_ws, size_t ws_size,
                              hipStream_t stream)
{
    (void)in_sizes; (void)n_in; (void)out_size;
    const int*   ids   = (const int*)d_in[0];
    const float* emb   = (const float*)d_in[2];
    const float* wih_f = (const float*)d_in[3];
    const float* whh_f = (const float*)d_in[4];
    const float* bih_f = (const float*)d_in[5];
    const float* bhh_f = (const float*)d_in[6];
    const float* wih_b = (const float*)d_in[7];
    const float* whh_b = (const float*)d_in[8];
    const float* bih_b = (const float*)d_in[9];
    const float* bhh_b = (const float*)d_in[10];
    const float* ws1   = (const float*)d_in[11];
    const float* ws2   = (const float*)d_in[12];
    const float* caps  = (const float*)d_in[13];
    float* out = (float*)d_out;   // fp32 outputs

    // Workspace (word offsets); capsT16 aliases low region after n_attsem.
    float* ws = (float*)d_ws;
    f16*  hs16   = (f16*)ws;                          // 8,388,608 w
    f16*  hx     = (f16*)(ws + 8388608);              //   262,144 w
    f16*  X16    = (f16*)(ws + 8650752);              // 2,621,440 w
    f16*  W16    = (f16*)(ws + 11272192);             // 1,703,936 w
    f16*  ws1_16 = (f16*)(ws + 12976128);             //   196,608 w
    f16*  sem16  = (f16*)(ws + 13172736);             // 1,048,576 w
    unsigned* pflag = (unsigned*)(ws + 14221312);     //     4,096 w
    f16*  pre16  = X16;                               // alias (post-LSTM)
    f16*  capsT16 = (f16*)ws;                         // alias (post-attsem)
    const size_t need = (size_t)(14221312 + NPF) * 4;
    if (ws_size < need) return;

    // Fused staging (X16 | W16 | ws1_16 | pflag)
    {
        const long total = NG_ + NW_ + NS_ + NPF;
        n_stage<<<(int)((total + 255) / 256), 256, 0, stream>>>(
            ids, emb, wih_f, whh_f, wih_b, whh_b, ws1, X16, W16, ws1_16, pflag);
    }

    // Persistent LSTM (v8: per-producer flags, wave-parallel poll)
    {
        const f16* a0 = X16; f16* a1 = hs16; f16* a2 = hx; unsigned* a3 = pflag;
        const f16* a4 = W16;
        const float* a5 = bih_f; const float* a6 = bhh_f;
        const float* a7 = bih_b; const float* a8 = bhh_b;
        void* kargs[] = {(void*)&a0, (void*)&a1, (void*)&a2, (void*)&a3, (void*)&a4,
                         (void*)&a5, (void*)&a6, (void*)&a7, (void*)&a8};
        hipLaunchCooperativeKernel((void*)p_lstm8, dim3(256), dim3(512),
                                   kargs, 0, stream);
    }

    // pre16 = tanh(hs16 @ ws1^T), f16 out
    n_preG<<<dim3(2, 256), 256, 0, stream>>>(hs16, ws1_16, pre16);

    // fused attention + semantic (att -> d_out, sem -> sem16)
    n_attsem<<<BB, 256, 0, stream>>>(pre16, ws2, hs16, out + ATT_OFF, sem16);

    // caps -> capsT16 (hs16 region dead after n_attsem)
    n_packcapsT<<<dim3(32, 76, 8), 256, 0, stream>>>(caps, capsT16);

    // pred = sem16 @ caps, fp32 out
    n_predG<<<dim3(38, 8), 512, 0, stream>>>(sem16, capsT16, out + PRED_OFF);

    n_route<<<BB, 512, 0, stream>>>(out + PRED_OFF, out + CL_OFF, out + ROUTES_OFF);
}

// Round 22
// 740.954 us; speedup vs baseline: 1.2006x; 1.0560x over previous
//
#include <hip/hip_runtime.h>
#include <hip/hip_bf16.h>
#include <hip/hip_cooperative_groups.h>
#include <math.h>

// Sizes
#define BB 256
#define SS 64
#define EE 300
#define EPX 320   // X padded
#define KP 832    // 320 + 512
#define VV 30000
#define HH 512
#define H2 1024
#define DA 350
#define RR 8
#define CC 150
#define PP 16
#define CP 2400
#define NPF 4096  // per-producer flags: 256 blocks x 16 u32 (64B padded lines)

// Output layout (elements, fp32)
#define ATT_OFF    0L
#define CL_OFF     131072L
#define PRED_OFF   169472L
#define ROUTES_OFF 5084672L

typedef _Float16 f16;
typedef f16  f16x8 __attribute__((ext_vector_type(8)));
typedef f16  f16x4 __attribute__((ext_vector_type(4)));
typedef f16  f16x2 __attribute__((ext_vector_type(2)));
typedef float f32x4 __attribute__((ext_vector_type(4)));

static __device__ __forceinline__ float sigmQ(float x) { return 1.0f / (1.0f + expf(-x)); }

// ---------------------------------------------------------------------------
// Fused staging: X16 gather | W16 pack | ws1_16 pack | pflag zero.
// ---------------------------------------------------------------------------
#define NG_ ((long)SS * BB * EPX)        // 5,242,880
#define NW_ ((long)2 * 2048 * KP)        // 3,407,872
#define NS_ ((long)384 * 1024)           //   393,216
__global__ __launch_bounds__(256) void q_stage(
    const int* __restrict__ ids, const float* __restrict__ emb,
    const float* __restrict__ wihF, const float* __restrict__ whhF,
    const float* __restrict__ wihB, const float* __restrict__ whhB,
    const float* __restrict__ ws1,
    f16* __restrict__ X16, f16* __restrict__ W16, f16* __restrict__ ws1_16,
    unsigned* __restrict__ pflag)
{
    const long idx = (long)blockIdx.x * 256 + threadIdx.x;
    if (idx < NG_) {
        const int e = (int)(idx % EPX);
        const int row = (int)(idx / EPX);
        const int s = row >> 8, b = row & 255;
        int tok = ids[(long)b * SS + s];
        if ((unsigned)tok >= (unsigned)VV) tok = 0;
        X16[idx] = (e < EE) ? (f16)emb[(long)tok * EE + e] : (f16)0.0f;
    } else if (idx < NG_ + NW_) {
        const long i2 = idx - NG_;
        const int dir = (int)(i2 / (2048 * KP));
        const int rem = (int)(i2 % (2048 * KP));
        const int j = rem / KP, k = rem % KP;
        const float* wih = dir ? wihB : wihF;
        const float* whh = dir ? whhB : whhF;
        float v;
        if (k < EE)        v = wih[(long)j * EE + k];
        else if (k < EPX)  v = 0.0f;
        else               v = whh[(long)j * HH + (k - EPX)];
        W16[i2] = (f16)v;
    } else if (idx < NG_ + NW_ + NS_) {
        const long i3 = idx - NG_ - NW_;
        const int j = (int)(i3 >> 10);
        ws1_16[i3] = (j < DA) ? (f16)ws1[i3] : (f16)0.0f;
    } else if (idx < NG_ + NW_ + NS_ + NPF) {
        pflag[idx - NG_ - NW_ - NS_] = 0u;
    }
}

// capsT16[r][2432][1024] transposed; rows >= 2400 zero. LDS 32x32 tiles.
__global__ __launch_bounds__(256) void q_packcapsT(
    const float* __restrict__ caps, f16* __restrict__ capsT)
{
    __shared__ float t[32][33];
    const int r = blockIdx.z, k0 = blockIdx.x * 32, n0 = blockIdx.y * 32;
    const int tx = threadIdx.x & 31, ty = threadIdx.x >> 5;
    #pragma unroll
    for (int p = 0; p < 4; ++p) {
        const int k = k0 + ty + p * 8;
        const int n = n0 + tx;
        t[ty + p * 8][tx] = (n < CP) ? caps[((long)r * H2 + k) * CP + n] : 0.0f;
    }
    __syncthreads();
    #pragma unroll
    for (int p = 0; p < 4; ++p) {
        const int n = n0 + ty + p * 8;
        if (n < 2432)
            capsT[((long)r * 2432 + n) * H2 + k0 + tx] = (f16)t[tx][ty + p * 8];
    }
}

// ---------------------------------------------------------------------------
// Persistent LSTM v9 = v8 with a shortened serial chain:
//  (1) 2 barriers/step (was 3): kh0 waves store their OWN hstage rows to hx
//      (intra-wave transpose, lgkmcnt+sched_barrier discipline), drain with
//      per-wave vmcnt(0), and post fetch_add(+1) on the block's own line.
//      Consumer threshold = 4*s (4 kh0 waves per producer block).
//  Safety: flags(s)==4*32 => every kh0 wave passed barrier B(s) => all
//  hx(s-1) reads consumed => parity reuse at s+1 safe. part[] protected by
//  barrier A(s+1) (kh1's next write waits for kh0's read via block barrier).
//  (2) per-producer padded flag lines + wave-parallel detection (v8).
//  (3) conflict-free part layout [bt][g][lane] (v8).
// ---------------------------------------------------------------------------
__global__ __launch_bounds__(512, 1) void p_lstm9(
    const f16* __restrict__ X16, f16* __restrict__ hs16,
    f16* __restrict__ hx, unsigned* __restrict__ pflag,
    const f16* __restrict__ W16,
    const float* __restrict__ bihF, const float* __restrict__ bhhF,
    const float* __restrict__ bihB, const float* __restrict__ bhhB)
{
    __shared__ f16 Wl[4 * 26 * 64 * 8];   // 104 KB
    __shared__ f32x4 part[4][4][64];      // 16 KB, conflict-free
    __shared__ f16 hstage[64][16];        // 2 KB

    const int bid = blockIdx.x;
    const int dir = bid & 1;
    const int bq  = (bid >> 1) & 3;
    const int ut  = bid >> 3;
    const int u0  = ut * 16;
    const int b0  = bq * 64;
    const int tid = threadIdx.x;
    const int wave = tid >> 6, lane = tid & 63;
    const int bt = wave & 3, kh = wave >> 2;
    const int l15 = lane & 15;
    const int kgrp = (lane >> 4) * 8;
    const int grp32 = (dir * 4 + bq) * 32;
    unsigned* myflag = pflag + (grp32 + ut) * 16;

    // One-time weight gather into fragment order
    {
        const f16* Wsrc = W16 + (long)dir * 2048 * KP;
        for (int f = tid; f < 4 * 26 * 64; f += 512) {
            const int g  = f / (26 * 64);
            const int rm = f % (26 * 64);
            const int kt = rm >> 6, ln = rm & 63;
            const long src = ((long)g * HH + u0 + (ln & 15)) * KP + kt * 32 + ((ln >> 4) * 8);
            *(f16x8*)(Wl + (long)f * 8) = *(const f16x8*)(Wsrc + src);
        }
    }
    __syncthreads();

    const int arow = b0 + bt * 16 + l15;
    const int u = u0 + l15;
    const float* bi = dir ? bihB : bihF;
    const float* bh = dir ? bhhB : bhhF;
    const float bias0 = bi[u]          + bh[u];
    const float bias1 = bi[HH + u]     + bh[HH + u];
    const float bias2 = bi[2 * HH + u] + bh[2 * HH + u];
    const float bias3 = bi[3 * HH + u] + bh[3 * HH + u];
    const int rbase = (lane >> 4) * 4;
    float cc[4] = {0.f, 0.f, 0.f, 0.f};

    f32x4 xacc[4];
    const int xb = kh ? 5 : 0;
    auto computeX = [&](int se) {
        #pragma unroll
        for (int g = 0; g < 4; ++g) xacc[g] = (f32x4){0.f, 0.f, 0.f, 0.f};
        const f16* Xrow = X16 + ((long)se * BB + arow) * EPX;
        #pragma unroll
        for (int j = 0; j < 5; ++j) {
            const int kt = xb + j;
            const int k0 = kt * 32 + kgrp;
            const f16x8 afr = *(const f16x8*)(Xrow + k0);
            #pragma unroll
            for (int g = 0; g < 4; ++g) {
                const f16x8 bfr = *(const f16x8*)(Wl + (((g * 26 + kt) << 6) + lane) * 8);
                xacc[g] = __builtin_amdgcn_mfma_f32_16x16x32_f16(afr, bfr, xacc[g], 0, 0, 0);
            }
        }
    };
    computeX(dir ? (SS - 1) : 0);

    const int hb = kh ? 8 : 0;
    for (int s = 0; s < SS; ++s) {
        const int s_eff = dir ? (SS - 1 - s) : s;

        // barrier A: wave 0 polls 32 producer lines (threshold 4*s)
        if (s > 0) {
            if (wave == 0) {
                const unsigned* fp = pflag + (grp32 + (lane & 31)) * 16;
                const unsigned target = 4u * (unsigned)s;
                int guard = 0;
                unsigned v = __hip_atomic_load(fp, __ATOMIC_RELAXED,
                                               __HIP_MEMORY_SCOPE_AGENT);
                while (!__all((int)(v >= target))) {
                    __builtin_amdgcn_s_sleep(1);
                    v = __hip_atomic_load(fp, __ATOMIC_RELAXED,
                                          __HIP_MEMORY_SCOPE_AGENT);
                    if (++guard > (1 << 22)) break;   // fail loud, not hung
                }
            }
            __syncthreads();
        }

        f32x4 acc[4];
        #pragma unroll
        for (int g = 0; g < 4; ++g) acc[g] = xacc[g];

        if (s > 0) {
            const f16* hrow = hx + ((((long)((s - 1) & 1) * 2 + dir) * BB) + arow) * HH;
            #pragma unroll
            for (int j = 0; j < 8; ++j) {
                const int kt = 10 + hb + j;
                const int hk = (hb + j) * 32 + kgrp;
                union { unsigned long long q[2]; f16x8 v; } uu;
                const unsigned long long* hp = (const unsigned long long*)(hrow + hk);
                uu.q[0] = __hip_atomic_load(hp,     __ATOMIC_RELAXED, __HIP_MEMORY_SCOPE_AGENT);
                uu.q[1] = __hip_atomic_load(hp + 1, __ATOMIC_RELAXED, __HIP_MEMORY_SCOPE_AGENT);
                #pragma unroll
                for (int g = 0; g < 4; ++g) {
                    const f16x8 bfr = *(const f16x8*)(Wl + (((g * 26 + kt) << 6) + lane) * 8);
                    acc[g] = __builtin_amdgcn_mfma_f32_16x16x32_f16(uu.v, bfr, acc[g], 0, 0, 0);
                }
            }
        }

        if (kh == 1) {
            #pragma unroll
            for (int g = 0; g < 4; ++g) part[bt][g][lane] = acc[g];
        }
        __syncthreads();   // barrier B

        if (kh == 0) {
            #pragma unroll
            for (int g = 0; g < 4; ++g) acc[g] += part[bt][g][lane];
            #pragma unroll
            for (int i = 0; i < 4; ++i) {
                const float zi = acc[0][i] + bias0;
                const float zf = acc[1][i] + bias1;
                const float zg = acc[2][i] + bias2;
                const float zo = acc[3][i] + bias3;
                cc[i] = sigmQ(zf) * cc[i] + sigmQ(zi) * tanhf(zg);
                hstage[bt * 16 + rbase + i][l15] = (f16)(sigmQ(zo) * tanhf(cc[i]));
            }
            asm volatile("s_waitcnt lgkmcnt(0)" ::: "memory");
            __builtin_amdgcn_sched_barrier(0);

            // per-wave hx store of OWN rows (intra-wave transpose readback)
            const int row = bt * 16 + (lane >> 2), ch = lane & 3;
            union { unsigned long long q; f16 h4[4]; } pk;
            pk.h4[0] = hstage[row][ch * 4 + 0];
            pk.h4[1] = hstage[row][ch * 4 + 1];
            pk.h4[2] = hstage[row][ch * 4 + 2];
            pk.h4[3] = hstage[row][ch * 4 + 3];
            __hip_atomic_store(
                (unsigned long long*)(hx + (((long)(s & 1) * 2 + dir) * BB
                                            + b0 + row) * HH + u0 + ch * 4),
                pk.q, __ATOMIC_RELAXED, __HIP_MEMORY_SCOPE_AGENT);
            asm volatile("s_waitcnt vmcnt(0)" ::: "memory");
            if (lane == 0)
                __hip_atomic_fetch_add(myflag, 1u, __ATOMIC_RELAXED,
                                       __HIP_MEMORY_SCOPE_AGENT);

            // hs16 archive: off the critical path
            *(unsigned long long*)(hs16 + ((long)(b0 + row) * SS + s_eff) * H2
                                   + dir * HH + u0 + ch * 4) = pk.q;
        }

        // prefetch x-part for next step (overlaps the next wait)
        if (s + 1 < SS) computeX(dir ? (SS - 2 - s) : (s + 1));
    }
}

// ---------------------------------------------------------------------------
// pre GEMM: 64 m x 96 n (nt=6), grid (4, 256) = 1024 blocks (2x TLP).
// ---------------------------------------------------------------------------
__global__ __launch_bounds__(256) void q_preG(
    const f16* __restrict__ hs16, const f16* __restrict__ ws1_16,
    f16* __restrict__ pre16)
{
    const int n0 = blockIdx.x * 96;
    const int m0 = blockIdx.y * 64;
    const int tid = threadIdx.x;
    const int wave = tid >> 6, lane = tid & 63;
    const int l15 = lane & 15;
    const int kgrp = (lane >> 4) * 8;
    const f16* Arow = hs16 + (long)(m0 + wave * 16 + l15) * H2;

    f32x4 acc[6];
    #pragma unroll
    for (int nt = 0; nt < 6; ++nt) acc[nt] = (f32x4){0.f, 0.f, 0.f, 0.f};

    for (int kt = 0; kt < 32; ++kt) {
        const int k0 = kt * 32 + kgrp;
        const f16x8 afr = *(const f16x8*)(Arow + k0);
        #pragma unroll
        for (int nt = 0; nt < 6; ++nt) {
            const f16x8 bfr = *(const f16x8*)(ws1_16 + (long)(n0 + nt * 16 + l15) * H2 + k0);
            acc[nt] = __builtin_amdgcn_mfma_f32_16x16x32_f16(afr, bfr, acc[nt], 0, 0, 0);
        }
    }

    const int rbase = (lane >> 4) * 4;
    #pragma unroll
    for (int nt = 0; nt < 6; ++nt) {
        const int n = n0 + nt * 16 + l15;
        if (n < DA) {
            #pragma unroll
            for (int i = 0; i < 4; ++i) {
                const int m = m0 + wave * 16 + rbase + i;
                pre16[(long)m * DA + n] = (f16)tanhf(acc[nt][i]);
            }
        }
    }
}

// ---------------------------------------------------------------------------
// Fused attention + semantic, 512 threads, fdot2 logits.
// ---------------------------------------------------------------------------
__global__ __launch_bounds__(512) void q_attsem(
    const f16* __restrict__ pre16, const float* __restrict__ ws2,
    const f16* __restrict__ hs16,
    float* __restrict__ att_out, f16* __restrict__ sem16)
{
    __shared__ f16 preS[SS * DA];     // 44.8 KB
    __shared__ f16 w2f[RR * DA];      // 5.6 KB
    __shared__ float logS[RR * SS];   // 2 KB
    __shared__ float aS[RR * SS];     // 2 KB
    __shared__ float rmax[RR], rsum[RR];
    const int b = blockIdx.x, tid = threadIdx.x;
    {
        const unsigned long long* src =
            (const unsigned long long*)(pre16 + (long)b * SS * DA);
        unsigned long long* dst = (unsigned long long*)preS;
        for (int i = tid; i < SS * DA / 4; i += 512) dst[i] = src[i];
    }
    for (int i = tid; i < RR * DA; i += 512) w2f[i] = (f16)ws2[i];
    __syncthreads();
    {   // one (r,s) pair per thread; 175 packed dot2s
        const int r = tid >> 6, s = tid & 63;
        const f16x2* pv = (const f16x2*)&preS[s * DA];
        const f16x2* wv = (const f16x2*)&w2f[r * DA];
        float a = 0.0f;
        for (int k = 0; k < DA / 2; ++k)
            a = __builtin_amdgcn_fdot2(pv[k], wv[k], a, false);
        logS[r * SS + s] = a;
    }
    __syncthreads();
    if (tid < RR) {
        float mx = -1e30f;
        for (int s = 0; s < SS; ++s) mx = fmaxf(mx, logS[tid * SS + s]);
        float sm = 0.0f;
        for (int s = 0; s < SS; ++s) sm += expf(logS[tid * SS + s] - mx);
        rmax[tid] = mx; rsum[tid] = sm;
    }
    __syncthreads();
    {
        const int r = tid >> 6;
        const float v = expf(logS[tid] - rmax[r]) / rsum[r];
        att_out[(long)b * RR * SS + tid] = v;
        aS[tid] = v;
    }
    __syncthreads();

    // semantic: 2 d per thread
    const int d0 = tid * 2;
    float acc[RR][2] = {};
    const f16* hb = hs16 + (long)b * SS * H2;
    for (int s = 0; s < SS; ++s) {
        const f16x2 hv = *(const f16x2*)(hb + s * H2 + d0);
        const float h0 = hv[0], h1 = hv[1];
        #pragma unroll
        for (int r = 0; r < RR; ++r) {
            const float a = aS[r * SS + s];
            acc[r][0] = fmaf(a, h0, acc[r][0]);
            acc[r][1] = fmaf(a, h1, acc[r][1]);
        }
    }
    #pragma unroll
    for (int r = 0; r < RR; ++r) {
        f16x2 o; o[0] = (f16)acc[r][0]; o[1] = (f16)acc[r][1];
        *(f16x2*)(sem16 + ((long)b * RR + r) * H2 + d0) = o;
    }
}

// ---------------------------------------------------------------------------
// pred GEMM: 32-n tiles, grid (76, 8) = 608 blocks (2x TLP). 8 waves x 2 mt.
// ---------------------------------------------------------------------------
__global__ __launch_bounds__(512) void q_predG(
    const f16* __restrict__ sem16, const f16* __restrict__ capsT16,
    float* __restrict__ pred_out)
{
    const int n0 = blockIdx.x * 32;
    const int r  = blockIdx.y;
    const int tid = threadIdx.x;
    const int wave = tid >> 6, lane = tid & 63;
    const int l15 = lane & 15;
    const int kgrp = (lane >> 4) * 8;
    const f16* Bp = capsT16 + (long)r * 2432 * H2;
    const f16* A0 = sem16 + ((long)(wave * 32 + l15) * RR + r) * H2;

    f32x4 acc[2][2];
    #pragma unroll
    for (int mt = 0; mt < 2; ++mt)
        #pragma unroll
        for (int nt = 0; nt < 2; ++nt) acc[mt][nt] = (f32x4){0.f, 0.f, 0.f, 0.f};

    for (int kt = 0; kt < 32; ++kt) {
        const int k0 = kt * 32 + kgrp;
        const f16x8 a0 = *(const f16x8*)(A0 + k0);
        const f16x8 a1 = *(const f16x8*)(A0 + (long)16 * RR * H2 + k0);
        #pragma unroll
        for (int nt = 0; nt < 2; ++nt) {
            const f16x8 bfr = *(const f16x8*)(Bp + (long)(n0 + nt * 16 + l15) * H2 + k0);
            acc[0][nt] = __builtin_amdgcn_mfma_f32_16x16x32_f16(a0, bfr, acc[0][nt], 0, 0, 0);
            acc[1][nt] = __builtin_amdgcn_mfma_f32_16x16x32_f16(a1, bfr, acc[1][nt], 0, 0, 0);
        }
    }

    const int rbase = (lane >> 4) * 4;
    #pragma unroll
    for (int mt = 0; mt < 2; ++mt) {
        #pragma unroll
        for (int nt = 0; nt < 2; ++nt) {
            const int n = n0 + nt * 16 + l15;
            if (n < CP) {
                #pragma unroll
                for (int i = 0; i < 4; ++i) {
                    const int m = wave * 32 + mt * 16 + rbase + i;
                    pred_out[((long)m * RR + r) * CP + n] = acc[mt][nt][i];
                }
            }
        }
    }
}

// ---------------------------------------------------------------------------
// Dynamic routing, 512 threads.
// ---------------------------------------------------------------------------
__global__ __launch_bounds__(512) void q_route(
    const float* __restrict__ pred,
    float* __restrict__ cls_out, float* __restrict__ routes_out)
{
    __shared__ float predS[RR * CP];
    __shared__ float logitS[RR * CC];
    __shared__ float routeS[RR * CC];
    __shared__ float preactS[CP];
    __shared__ float vS[CP];
    __shared__ float scaleS[CC];
    __shared__ float rmax[RR], rsum[RR];
    const int b = blockIdx.x, tid = threadIdx.x;
    const float* ps = pred + (long)b * RR * CP;
    for (int i = tid; i < RR * CP; i += 512) predS[i] = ps[i];
    for (int i = tid; i < RR * CC; i += 512) logitS[i] = 0.0f;
    __syncthreads();

    for (int it = 0; it < 3; ++it) {
        if (tid < RR) {
            float mx = -1e30f;
            for (int c = 0; c < CC; ++c) mx = fmaxf(mx, logitS[tid * CC + c]);
            float sm = 0.0f;
            for (int c = 0; c < CC; ++c) sm += expf(logitS[tid * CC + c] - mx);
            rmax[tid] = mx; rsum[tid] = sm;
        }
        __syncthreads();
        for (int i = tid; i < RR * CC; i += 512) {
            const int r = i / CC;
            routeS[i] = expf(logitS[i] - rmax[r]) / rsum[r];
        }
        __syncthreads();
        for (int cp = tid; cp < CP; cp += 512) {
            const int c = cp >> 4;
            float a = 0.0f;
            #pragma unroll
            for (int r = 0; r < RR; ++r)
                a = fmaf(routeS[r * CC + c], predS[r * CP + cp], a);
            preactS[cp] = a;
        }
        __syncthreads();
        for (int c = tid; c < CC; c += 512) {
            float n2 = 0.0f;
            #pragma unroll
            for (int p = 0; p < PP; ++p) { const float x = preactS[c * PP + p]; n2 = fmaf(x, x, n2); }
            scaleS[c] = (n2 / (1.0f + n2)) / sqrtf(n2 + 1e-9f);
        }
        __syncthreads();
        for (int cp = tid; cp < CP; cp += 512) vS[cp] = preactS[cp] * scaleS[cp >> 4];
        __syncthreads();
        for (int i = tid; i < RR * CC; i += 512) {
            const int r = i / CC, c = i % CC;
            float a = 0.0f;
            #pragma unroll
            for (int p = 0; p < PP; ++p)
                a = fmaf(predS[r * CP + c * PP + p], vS[c * PP + p], a);
            logitS[i] += a;
        }
        __syncthreads();
    }

    for (int i = tid; i < RR * CC; i += 512)
        routes_out[(long)b * RR * CC + i] = routeS[i];
    for (int c = tid; c < CC; c += 512) {
        float n2 = 0.0f;
        #pragma unroll
        for (int p = 0; p < PP; ++p) { const float x = vS[c * PP + p]; n2 = fmaf(x, x, n2); }
        cls_out[(long)b * CC + c] = sqrtf(n2);
    }
}

// ---------------------------------------------------------------------------
extern "C" void kernel_launch(void* const* d_in, const int* in_sizes, int n_in,
                              void* d_out, int out_size, void* d_ws, size_t ws_size,
                              hipStream_t stream)
{
    (void)in_sizes; (void)n_in; (void)out_size;
    const int*   ids   = (const int*)d_in[0];
    const float* emb   = (const float*)d_in[2];
    const float* wih_f = (const float*)d_in[3];
    const float* whh_f = (const float*)d_in[4];
    const float* bih_f = (const float*)d_in[5];
    const float* bhh_f = (const float*)d_in[6];
    const float* wih_b = (const float*)d_in[7];
    const float* whh_b = (const float*)d_in[8];
    const float* bih_b = (const float*)d_in[9];
    const float* bhh_b = (const float*)d_in[10];
    const float* ws1   = (const float*)d_in[11];
    const float* ws2   = (const float*)d_in[12];
    const float* caps  = (const float*)d_in[13];
    float* out = (float*)d_out;   // fp32 outputs

    // Workspace (word offsets); capsT16 aliases low region after q_attsem.
    float* ws = (float*)d_ws;
    f16*  hs16   = (f16*)ws;                          // 8,388,608 w
    f16*  hx     = (f16*)(ws + 8388608);              //   262,144 w
    f16*  X16    = (f16*)(ws + 8650752);              // 2,621,440 w
    f16*  W16    = (f16*)(ws + 11272192);             // 1,703,936 w
    f16*  ws1_16 = (f16*)(ws + 12976128);             //   196,608 w
    f16*  sem16  = (f16*)(ws + 13172736);             // 1,048,576 w
    unsigned* pflag = (unsigned*)(ws + 14221312);     //     4,096 w
    f16*  pre16  = X16;                               // alias (post-LSTM)
    f16*  capsT16 = (f16*)ws;                         // alias (post-attsem)
    const size_t need = (size_t)(14221312 + NPF) * 4;
    if (ws_size < need) return;

    // Fused staging (X16 | W16 | ws1_16 | pflag)
    {
        const long total = NG_ + NW_ + NS_ + NPF;
        q_stage<<<(int)((total + 255) / 256), 256, 0, stream>>>(
            ids, emb, wih_f, whh_f, wih_b, whh_b, ws1, X16, W16, ws1_16, pflag);
    }

    // Persistent LSTM (v9: 2 barriers/step, per-wave flag posts)
    {
        const f16* a0 = X16; f16* a1 = hs16; f16* a2 = hx; unsigned* a3 = pflag;
        const f16* a4 = W16;
        const float* a5 = bih_f; const float* a6 = bhh_f;
        const float* a7 = bih_b; const float* a8 = bhh_b;
        void* kargs[] = {(void*)&a0, (void*)&a1, (void*)&a2, (void*)&a3, (void*)&a4,
                         (void*)&a5, (void*)&a6, (void*)&a7, (void*)&a8};
        hipLaunchCooperativeKernel((void*)p_lstm9, dim3(256), dim3(512),
                                   kargs, 0, stream);
    }

    // pre16 = tanh(hs16 @ ws1^T), f16 out
    q_preG<<<dim3(4, 256), 256, 0, stream>>>(hs16, ws1_16, pre16);

    // fused attention + semantic
    q_attsem<<<BB, 512, 0, stream>>>(pre16, ws2, hs16, out + ATT_OFF, sem16);

    // caps -> capsT16 (hs16 region dead after q_attsem)
    q_packcapsT<<<dim3(32, 76, 8), 256, 0, stream>>>(caps, capsT16);

    // pred = sem16 @ caps, fp32 out
    q_predG<<<dim3(76, 8), 512, 0, stream>>>(sem16, capsT16, out + PRED_OFF);

    q_route<<<BB, 512, 0, stream>>>(out + PRED_OFF, out + CL_OFF, out + ROUTES_OFF);
}